// Round 2
// baseline (782.573 us; speedup 1.0000x reference)
//
#include <hip/hip_runtime.h>
#include <hip/hip_bf16.h>
#include <cmath>
#include <cstdint>

#define NNODES 2048
#define NEDGES 8192
#define NCH 64
#define NHID 64
#define NPATH 34
#define TTOT 738      // sum over paths of (2l1+1)*(2l3+1)
#define CGTOT 3436    // sum over paths of (2l1+1)*(2l2+1)*(2l3+1)
#define MROW 9984     // per-node m_i size = sum_l3 (2l3+1)*K_l3
#define MI_BYTES ((size_t)NNODES * MROW * 2)   // bf16 m_i in d_ws = 40,894,464 B

// ---------------- path tables (compile-time) ----------------
struct PathTables {
  int l1[NPATH], l2[NPATH], l3[NPATH];
  int cg_off[NPATH], t_off[NPATH], rank[NPATH];
  unsigned char t_path[TTOT];
  int cg_total, t_total, npaths;
};

constexpr PathTables make_tables() {
  PathTables tb{};
  int np = 0;
  for (int a = 0; a < 4; ++a)
    for (int b = 0; b < 4; ++b) {
      int lo = a > b ? a - b : b - a;
      int hi = a + b < 3 ? a + b : 3;
      for (int c = lo; c <= hi; ++c) { tb.l1[np] = a; tb.l2[np] = b; tb.l3[np] = c; ++np; }
    }
  int cg = 0, tt = 0;
  int cnt[4] = {0, 0, 0, 0};
  for (int i = 0; i < np; ++i) {
    tb.cg_off[i] = cg; tb.t_off[i] = tt; tb.rank[i] = cnt[tb.l3[i]]++;
    int d1 = 2 * tb.l1[i] + 1, d2 = 2 * tb.l2[i] + 1, d3 = 2 * tb.l3[i] + 1;
    cg += d1 * d2 * d3;
    for (int k = 0; k < d1 * d3; ++k) tb.t_path[tt + k] = (unsigned char)i;
    tt += d1 * d3;
  }
  tb.cg_total = cg; tb.t_total = tt; tb.npaths = np;
  return tb;
}

constexpr PathTables H_TB = make_tables();
static_assert(H_TB.npaths == NPATH, "npaths");
static_assert(H_TB.cg_total == CGTOT, "cgtot");
static_assert(H_TB.t_total == TTOT, "ttot");

__constant__ PathTables d_tb = make_tables();   // constexpr init — part of module image, no runtime copy

// ---------------- NumPy legacy RandomState(1234) reproduction (host) ----------------
namespace {
struct MT19937 {
  uint32_t mt[624]; int mti; bool has_g; double gval;
  void seed(uint32_t s) {
    for (int i = 0; i < 624; ++i) { mt[i] = s; s = 1812433253u * (s ^ (s >> 30)) + (uint32_t)i + 1u; }
    mti = 624; has_g = false; gval = 0.0;
  }
  uint32_t next() {
    if (mti >= 624) {
      for (int i = 0; i < 624; ++i) {
        uint32_t y = (mt[i] & 0x80000000u) | (mt[(i + 1) % 624] & 0x7fffffffu);
        mt[i] = mt[(i + 397) % 624] ^ (y >> 1) ^ ((y & 1u) ? 0x9908b0dfu : 0u);
      }
      mti = 0;
    }
    uint32_t y = mt[mti++];
    y ^= y >> 11; y ^= (y << 7) & 0x9d2c5680u; y ^= (y << 15) & 0xefc60000u; y ^= y >> 18;
    return y;
  }
  double rdbl() {
    uint32_t a = next() >> 5, b = next() >> 6;
    return ((double)a * 67108864.0 + (double)b) / 9007199254740992.0;
  }
  double gauss() {   // numpy legacy rk_gauss (polar, cached across calls)
    if (has_g) { has_g = false; return gval; }
    double x1, x2, r2;
    do {
      x1 = 2.0 * rdbl() - 1.0;
      x2 = 2.0 * rdbl() - 1.0;
      r2 = x1 * x1 + x2 * x2;
    } while (r2 >= 1.0 || r2 == 0.0);
    double f = std::sqrt(-2.0 * std::log(r2) / r2);
    gval = f * x1; has_g = true;
    return f * x2;
  }
};

float host_cg[CGTOT];
float* g_cg_dev = nullptr;   // device copy, allocated at dlopen (legal outside kernel_launch)
bool g_cg_ok = false;

struct CGInit {
  CGInit() {
    MT19937 g; g.seed(1234u);
    int idx = 0;
    for (int i = 0; i < NPATH; ++i) {
      int d1 = 2 * H_TB.l1[i] + 1, d2 = 2 * H_TB.l2[i] + 1, d3 = 2 * H_TB.l3[i] + 1;
      int sz = d1 * d2 * d3;
      for (int k = 0; k < sz; ++k) host_cg[idx++] = (float)(g.gauss() * 0.2);
    }
    // Plain hipMalloc + hipMemcpy: no device-symbol registration dependency
    // (hipMemcpyToSymbol at static-init ran BEFORE clang's fatbin-registration
    // ctor and failed silently -> zero CG -> zero output in R0).
    void* p = nullptr;
    if (hipMalloc(&p, sizeof(host_cg)) == hipSuccess && p) {
      if (hipMemcpy(p, host_cg, sizeof(host_cg), hipMemcpyHostToDevice) == hipSuccess) {
        float back = 0.f;   // verify round-trip of last element
        if (hipMemcpy(&back, (float*)p + (CGTOT - 1), sizeof(float),
                      hipMemcpyDeviceToHost) == hipSuccess && back == host_cg[CGTOT - 1]) {
          g_cg_dev = (float*)p;
          g_cg_ok = true;
        }
      }
    }
  }
} cg_init_instance;
}  // namespace

// ---------------- kernel 1: per-node TP accumulation ----------------
// grid = NNODES blocks, 256 threads. m_out layout per node: [l3][m][k], k = rank*64 + c.
__global__ __launch_bounds__(256) void tp_node_kernel(
    const float* __restrict__ x0, const float* __restrict__ x1,
    const float* __restrict__ x2, const float* __restrict__ x3,
    const float* __restrict__ y0, const float* __restrict__ y1,
    const float* __restrict__ y2, const float* __restrict__ y3,
    const float* __restrict__ ws, const int* __restrict__ edge_index,
    const float* __restrict__ cg_g,
    __hip_bfloat16* __restrict__ m_out)
{
  __shared__ float m_acc[MROW];
  __shared__ float T_s[TTOT];
  __shared__ float y_s[16];
  __shared__ int elist[64];
  __shared__ int ecount;

  const int n = blockIdx.x;
  const int t = threadIdx.x;

  for (int j = t; j < MROW; j += 256) m_acc[j] = 0.f;
  if (t == 0) ecount = 0;
  __syncthreads();

  const int* __restrict__ srcs = edge_index;
  const int* __restrict__ dsts = edge_index + NEDGES;
  for (int e = t; e < NEDGES; e += 256)
    if (dsts[e] == n) { int p = atomicAdd(&ecount, 1); if (p < 64) elist[p] = e; }
  __syncthreads();
  const int cnt = ecount < 64 ? ecount : 64;

  const float* xs_[4] = {x0, x1, x2, x3};
  constexpr int roff[4]  = {0, 256, 1984, 5504};
  constexpr int kdim[4]  = {256, 576, 704, 640};
  constexpr int ybase[4] = {0, 1, 4, 9};

  for (int ei = 0; ei < cnt; ++ei) {
    const int e = elist[ei];
    const int s = srcs[e];
    if (t < 16) {
      float v;
      if (t < 1)      v = y0[e];
      else if (t < 4) v = y1[e * 3 + (t - 1)];
      else if (t < 9) v = y2[e * 5 + (t - 4)];
      else            v = y3[e * 7 + (t - 9)];
      y_s[t] = v;
    }
    __syncthreads();

    // T[i][l][n3] = sum_m CG[i][l][m][n3] * y_{l2}[m]
    for (int tt = t; tt < TTOT; tt += 256) {
      const int i   = d_tb.t_path[tt];
      const int l2v = d_tb.l2[i], l3v = d_tb.l3[i];
      const int d2  = 2 * l2v + 1, d3 = 2 * l3v + 1;
      const int local = tt - d_tb.t_off[i];
      const int l   = local / d3;
      const int n3  = local - l * d3;
      const float* cg = cg_g + d_tb.cg_off[i] + l * d2 * d3 + n3;
      float acc = 0.f;
      for (int m = 0; m < d2; ++m) acc += cg[m * d3] * y_s[ybase[l2v] + m];
      T_s[tt] = acc;
    }
    __syncthreads();

    // tasks = (path, channel); wave-uniform path (task>>6 constant per wave)
    for (int task = t; task < NPATH * NCH; task += 256) {
      const int i = task >> 6;
      const int c = task & 63;
      const int l1v = d_tb.l1[i], l3v = d_tb.l3[i];
      const int d1 = 2 * l1v + 1, d3 = 2 * l3v + 1;
      const float* xr = xs_[l1v] + (size_t)(s * NCH + c) * d1;
      const float* Tp = T_s + d_tb.t_off[i];
      float u[7];
#pragma unroll
      for (int m = 0; m < 7; ++m) u[m] = 0.f;
      for (int l = 0; l < d1; ++l) {
        const float xv = xr[l];
#pragma unroll
        for (int m = 0; m < 7; ++m) {
          float tv = (m < d3) ? Tp[l * d3 + m] : 0.f;
          u[m] += xv * tv;
        }
      }
      const float w = ws[(size_t)e * (NPATH * NCH) + task];
      float* mp = m_acc + roff[l3v] + d_tb.rank[i] * NCH + c;
      const int K = kdim[l3v];
#pragma unroll
      for (int m = 0; m < 7; ++m)
        if (m < d3) mp[m * K] += w * u[m];
    }
    __syncthreads();
  }

  __hip_bfloat16* mo = m_out + (size_t)n * MROW;
  for (int j = t; j < MROW; j += 256) mo[j] = __float2bfloat16(m_acc[j]);
}

// ---------------- kernel 2: per-l3 linear (tiled GEMM) ----------------
// rows r = n*D3 + m (R = NNODES*D3, R%64==0), cols = 64 (h), contraction K.
template <int D3, int K, int ROFF>
__global__ __launch_bounds__(256) void lin_kernel(
    const __hip_bfloat16* __restrict__ m, const float* __restrict__ wl,
    float* __restrict__ out)
{
  __shared__ float A_s[64][65];
  __shared__ float W_s[64][64];
  const int t  = threadIdx.x;
  const int r0 = blockIdx.x * 64;
  const int hq = t & 15;   // h = hq*4 + j
  const int rq = t >> 4;   // r = r0 + rq*4 + i
  float acc[4][4] = {};

  for (int k0 = 0; k0 < K; k0 += 64) {
    for (int idx = t; idx < 4096; idx += 256) {
      int kk = idx >> 6, h = idx & 63;
      W_s[kk][h] = wl[(size_t)(k0 + kk) * 64 + h];
    }
    for (int idx = t; idx < 4096; idx += 256) {
      int rr = idx >> 6, kk = idx & 63;
      int r = r0 + rr;
      int nn = r / D3, mm = r - nn * D3;
      A_s[rr][kk] = __bfloat162float(m[(size_t)nn * MROW + ROFF + mm * K + k0 + kk]);
    }
    __syncthreads();
#pragma unroll
    for (int kk = 0; kk < 64; ++kk) {
      const float4 wv = *(const float4*)(&W_s[kk][hq * 4]);
#pragma unroll
      for (int i2 = 0; i2 < 4; ++i2) {
        const float a = A_s[rq * 4 + i2][kk];
        acc[i2][0] += a * wv.x;
        acc[i2][1] += a * wv.y;
        acc[i2][2] += a * wv.z;
        acc[i2][3] += a * wv.w;
      }
    }
    __syncthreads();
  }

#pragma unroll
  for (int i2 = 0; i2 < 4; ++i2) {
    int r = r0 + rq * 4 + i2;
    int nn = r / D3, mm = r - nn * D3;
#pragma unroll
    for (int j = 0; j < 4; ++j)
      out[((size_t)nn * NHID + hq * 4 + j) * D3 + mm] = acc[i2][j];
  }
}

// ---------------- launch ----------------
extern "C" void kernel_launch(void* const* d_in, const int* in_sizes, int n_in,
                              void* d_out, int out_size, void* d_ws, size_t ws_size,
                              hipStream_t stream) {
  // setup_inputs() dict order: x0,y0,w_lin0, x1,y1,w_lin1, x2,y2,w_lin2, x3,y3,w_lin3, ws, edge_index
  const float* x0  = (const float*)d_in[0];
  const float* y0  = (const float*)d_in[1];
  const float* wl0 = (const float*)d_in[2];
  const float* x1  = (const float*)d_in[3];
  const float* y1  = (const float*)d_in[4];
  const float* wl1 = (const float*)d_in[5];
  const float* x2  = (const float*)d_in[6];
  const float* y2  = (const float*)d_in[7];
  const float* wl2 = (const float*)d_in[8];
  const float* x3  = (const float*)d_in[9];
  const float* y3  = (const float*)d_in[10];
  const float* wl3 = (const float*)d_in[11];
  const float* ws  = (const float*)d_in[12];
  const int* edge_index = (const int*)d_in[13];
  float* out = (float*)d_out;

  __hip_bfloat16* m_i = (__hip_bfloat16*)d_ws;   // MI_BYTES = ~40.9 MB

  const float* cg_dev;
  if (g_cg_ok) {
    cg_dev = g_cg_dev;
  } else {
    // Fallback: stream-ordered H2D each call (graph-capturable memcpy node;
    // identical work every call). CG lives in the d_ws tail past m_i.
    float* cg_ws = (float*)((char*)d_ws + MI_BYTES);
    hipMemcpyAsync(cg_ws, host_cg, sizeof(host_cg), hipMemcpyHostToDevice, stream);
    cg_dev = cg_ws;
  }

  tp_node_kernel<<<NNODES, 256, 0, stream>>>(x0, x1, x2, x3, y0, y1, y2, y3,
                                             ws, edge_index, cg_dev, m_i);

  // res offsets in d_out: l3=0 at 0, l3=1 at 131072, l3=2 at 524288, l3=3 at 1179648
  lin_kernel<1, 256, 0>   <<<(NNODES * 1) / 64, 256, 0, stream>>>(m_i, wl0, out);
  lin_kernel<3, 576, 256> <<<(NNODES * 3) / 64, 256, 0, stream>>>(m_i, wl1, out + 131072);
  lin_kernel<5, 704, 1984><<<(NNODES * 5) / 64, 256, 0, stream>>>(m_i, wl2, out + 524288);
  lin_kernel<7, 640, 5504><<<(NNODES * 7) / 64, 256, 0, stream>>>(m_i, wl3, out + 1179648);
}

// Round 3
// 477.783 us; speedup vs baseline: 1.6379x; 1.6379x over previous
//
#include <hip/hip_runtime.h>
#include <hip/hip_bf16.h>
#include <cmath>
#include <cstdint>

#define NNODES 2048
#define NEDGES 8192
#define NCH 64
#define NHID 64
#define NPATH 34
#define NTASK (NPATH * NCH)   // 2176
#define TTOT 738      // sum over paths of (2l1+1)*(2l3+1)
#define CGTOT 3436    // sum over paths of (2l1+1)*(2l2+1)*(2l3+1)
#define MROW 9984     // per-node m_i size = sum_l3 (2l3+1)*K_l3
#define MI_BYTES ((size_t)NNODES * MROW * 2)            // bf16 m_i   = 40,894,464 B
#define T_BYTES  ((size_t)NEDGES * TTOT * 4)            // fp32 T     = 24,182,784 B
#define ECAP 96

// ---------------- path tables (compile-time) ----------------
struct PathTables {
  int l1[NPATH], l2[NPATH], l3[NPATH];
  int cg_off[NPATH], t_off[NPATH], rank[NPATH];
  unsigned char t_path[TTOT];
  int cg_total, t_total, npaths;
};

constexpr PathTables make_tables() {
  PathTables tb{};
  int np = 0;
  for (int a = 0; a < 4; ++a)
    for (int b = 0; b < 4; ++b) {
      int lo = a > b ? a - b : b - a;
      int hi = a + b < 3 ? a + b : 3;
      for (int c = lo; c <= hi; ++c) { tb.l1[np] = a; tb.l2[np] = b; tb.l3[np] = c; ++np; }
    }
  int cg = 0, tt = 0;
  int cnt[4] = {0, 0, 0, 0};
  for (int i = 0; i < np; ++i) {
    tb.cg_off[i] = cg; tb.t_off[i] = tt; tb.rank[i] = cnt[tb.l3[i]]++;
    int d1 = 2 * tb.l1[i] + 1, d2 = 2 * tb.l2[i] + 1, d3 = 2 * tb.l3[i] + 1;
    cg += d1 * d2 * d3;
    for (int k = 0; k < d1 * d3; ++k) tb.t_path[tt + k] = (unsigned char)i;
    tt += d1 * d3;
  }
  tb.cg_total = cg; tb.t_total = tt; tb.npaths = np;
  return tb;
}

constexpr PathTables H_TB = make_tables();
static_assert(H_TB.npaths == NPATH, "npaths");
static_assert(H_TB.cg_total == CGTOT, "cgtot");
static_assert(H_TB.t_total == TTOT, "ttot");

__constant__ PathTables d_tb = make_tables();

// ---------------- NumPy legacy RandomState(1234) reproduction (host) ----------------
namespace {
struct MT19937 {
  uint32_t mt[624]; int mti; bool has_g; double gval;
  void seed(uint32_t s) {
    for (int i = 0; i < 624; ++i) { mt[i] = s; s = 1812433253u * (s ^ (s >> 30)) + (uint32_t)i + 1u; }
    mti = 624; has_g = false; gval = 0.0;
  }
  uint32_t next() {
    if (mti >= 624) {
      for (int i = 0; i < 624; ++i) {
        uint32_t y = (mt[i] & 0x80000000u) | (mt[(i + 1) % 624] & 0x7fffffffu);
        mt[i] = mt[(i + 397) % 624] ^ (y >> 1) ^ ((y & 1u) ? 0x9908b0dfu : 0u);
      }
      mti = 0;
    }
    uint32_t y = mt[mti++];
    y ^= y >> 11; y ^= (y << 7) & 0x9d2c5680u; y ^= (y << 15) & 0xefc60000u; y ^= y >> 18;
    return y;
  }
  double rdbl() {
    uint32_t a = next() >> 5, b = next() >> 6;
    return ((double)a * 67108864.0 + (double)b) / 9007199254740992.0;
  }
  double gauss() {
    if (has_g) { has_g = false; return gval; }
    double x1, x2, r2;
    do {
      x1 = 2.0 * rdbl() - 1.0;
      x2 = 2.0 * rdbl() - 1.0;
      r2 = x1 * x1 + x2 * x2;
    } while (r2 >= 1.0 || r2 == 0.0);
    double f = std::sqrt(-2.0 * std::log(r2) / r2);
    gval = f * x1; has_g = true;
    return f * x2;
  }
};

float host_cg[CGTOT];
float* g_cg_dev = nullptr;
bool g_cg_ok = false;

struct CGInit {
  CGInit() {
    MT19937 g; g.seed(1234u);
    int idx = 0;
    for (int i = 0; i < NPATH; ++i) {
      int d1 = 2 * H_TB.l1[i] + 1, d2 = 2 * H_TB.l2[i] + 1, d3 = 2 * H_TB.l3[i] + 1;
      int sz = d1 * d2 * d3;
      for (int k = 0; k < sz; ++k) host_cg[idx++] = (float)(g.gauss() * 0.2);
    }
    void* p = nullptr;
    if (hipMalloc(&p, sizeof(host_cg)) == hipSuccess && p) {
      if (hipMemcpy(p, host_cg, sizeof(host_cg), hipMemcpyHostToDevice) == hipSuccess) {
        float back = 0.f;
        if (hipMemcpy(&back, (float*)p + (CGTOT - 1), sizeof(float),
                      hipMemcpyDeviceToHost) == hipSuccess && back == host_cg[CGTOT - 1]) {
          g_cg_dev = (float*)p;
          g_cg_ok = true;
        }
      }
    }
  }
} cg_init_instance;
}  // namespace

// ---------------- kernel 0: per-edge T precompute ----------------
// T[e][tt] = sum_m CG[i][l][m][n3] * y_{l2}[e][m], fully edge-parallel.
__global__ __launch_bounds__(256) void t_kernel(
    const float* __restrict__ y0, const float* __restrict__ y1,
    const float* __restrict__ y2, const float* __restrict__ y3,
    const float* __restrict__ cg_g, float* __restrict__ Tbuf)
{
  __shared__ float y_s[16];
  const int e = blockIdx.x;
  const int t = threadIdx.x;
  if (t < 16) {
    float v;
    if (t < 1)      v = y0[e];
    else if (t < 4) v = y1[e * 3 + (t - 1)];
    else if (t < 9) v = y2[e * 5 + (t - 4)];
    else            v = y3[e * 7 + (t - 9)];
    y_s[t] = v;
  }
  __syncthreads();
  constexpr int ybase[4] = {0, 1, 4, 9};
  float* To = Tbuf + (size_t)e * TTOT;
  for (int tt = t; tt < TTOT; tt += 256) {
    const int i   = d_tb.t_path[tt];
    const int l2v = d_tb.l2[i], l3v = d_tb.l3[i];
    const int d2  = 2 * l2v + 1, d3 = 2 * l3v + 1;
    const int local = tt - d_tb.t_off[i];
    const int l   = local / d3;
    const int n3  = local - l * d3;
    const float* cg = cg_g + d_tb.cg_off[i] + l * d2 * d3 + n3;
    float acc = 0.f;
    for (int m = 0; m < d2; ++m) acc += cg[m * d3] * y_s[ybase[l2v] + m];
    To[tt] = acc;
  }
}

// ---------------- kernel 1: per-node TP, register accumulation ----------------
// grid = NNODES, 256 threads. Thread task (i,c) owns m_i[n][l3][0..d3)[rank*64+c];
// loops over the node's edges with register accumulators — no syncs in the loop.
__global__ __launch_bounds__(256) void tp_node_kernel(
    const float* __restrict__ x0, const float* __restrict__ x1,
    const float* __restrict__ x2, const float* __restrict__ x3,
    const float* __restrict__ ws, const int* __restrict__ edge_index,
    const float* __restrict__ Tbuf,
    __hip_bfloat16* __restrict__ m_out)
{
  __shared__ int elist[ECAP];
  __shared__ int esrc[ECAP];
  __shared__ int ecount;

  const int n = blockIdx.x;
  const int t = threadIdx.x;
  if (t == 0) ecount = 0;
  __syncthreads();

  const int* __restrict__ srcs = edge_index;
  const int* __restrict__ dsts = edge_index + NEDGES;
  for (int e = t; e < NEDGES; e += 256)
    if (dsts[e] == n) { int p = atomicAdd(&ecount, 1); if (p < ECAP) elist[p] = e; }
  __syncthreads();
  const int cnt = ecount < ECAP ? ecount : ECAP;
  if (t < cnt) esrc[t] = srcs[elist[t]];
  __syncthreads();

  const float* xs_[4] = {x0, x1, x2, x3};
  constexpr int roff[4] = {0, 256, 1984, 5504};
  constexpr int kdim[4] = {256, 576, 704, 640};

  for (int task = t; task < NTASK; task += 256) {
    const int i = task >> 6;          // wave-uniform path
    const int c = task & 63;
    const int l1v = d_tb.l1[i], l3v = d_tb.l3[i];
    const int d1 = 2 * l1v + 1, d3 = 2 * l3v + 1;
    const int toff = d_tb.t_off[i];
    const float* __restrict__ xbase = xs_[l1v];

    float acc[7];
#pragma unroll
    for (int m = 0; m < 7; ++m) acc[m] = 0.f;

    for (int ei = 0; ei < cnt; ++ei) {
      const int e = elist[ei];
      const int s = esrc[ei];
      const float w = ws[(size_t)e * NTASK + task];            // coalesced
      const float* __restrict__ Tp = Tbuf + (size_t)e * TTOT + toff;  // wave-broadcast
      const float* __restrict__ xr = xbase + (size_t)(s * NCH + c) * d1;
      float u[7];
#pragma unroll
      for (int m = 0; m < 7; ++m) u[m] = 0.f;
      for (int l = 0; l < d1; ++l) {
        const float xv = xr[l];
#pragma unroll
        for (int m = 0; m < 7; ++m) {
          float tv = (m < d3) ? Tp[l * d3 + m] : 0.f;
          u[m] += xv * tv;
        }
      }
#pragma unroll
      for (int m = 0; m < 7; ++m)
        if (m < d3) acc[m] += w * u[m];
    }

    const int K = kdim[l3v];
    __hip_bfloat16* mo = m_out + (size_t)n * MROW + roff[l3v] + d_tb.rank[i] * NCH + c;
#pragma unroll
    for (int m = 0; m < 7; ++m)
      if (m < d3) mo[m * K] = __float2bfloat16(acc[m]);        // coalesced per wave
  }
}

// ---------------- kernel 2: fused per-l3 linear (tiled GEMM, one launch) ----------------
template <int D3, int K, int ROFF>
__device__ __forceinline__ void lin_body(
    int blk, const __hip_bfloat16* __restrict__ m, const float* __restrict__ wl,
    float* __restrict__ out, float (*A_s)[65], float (*W_s)[64])
{
  const int t  = threadIdx.x;
  const int r0 = blk * 64;
  const int hq = t & 15;
  const int rq = t >> 4;
  float acc[4][4] = {};

  for (int k0 = 0; k0 < K; k0 += 64) {
    for (int idx = t; idx < 4096; idx += 256) {
      int kk = idx >> 6, h = idx & 63;
      W_s[kk][h] = wl[(size_t)(k0 + kk) * 64 + h];
    }
    for (int idx = t; idx < 4096; idx += 256) {
      int rr = idx >> 6, kk = idx & 63;
      int r = r0 + rr;
      int nn = r / D3, mm = r - nn * D3;
      A_s[rr][kk] = __bfloat162float(m[(size_t)nn * MROW + ROFF + mm * K + k0 + kk]);
    }
    __syncthreads();
#pragma unroll
    for (int kk = 0; kk < 64; ++kk) {
      const float4 wv = *(const float4*)(&W_s[kk][hq * 4]);
#pragma unroll
      for (int i2 = 0; i2 < 4; ++i2) {
        const float a = A_s[rq * 4 + i2][kk];
        acc[i2][0] += a * wv.x;
        acc[i2][1] += a * wv.y;
        acc[i2][2] += a * wv.z;
        acc[i2][3] += a * wv.w;
      }
    }
    __syncthreads();
  }

#pragma unroll
  for (int i2 = 0; i2 < 4; ++i2) {
    int r = r0 + rq * 4 + i2;
    int nn = r / D3, mm = r - nn * D3;
#pragma unroll
    for (int j = 0; j < 4; ++j)
      out[((size_t)nn * NHID + hq * 4 + j) * D3 + mm] = acc[i2][j];
  }
}

// segments: l3=0: blocks [0,32) | l3=1: [32,128) | l3=2: [128,288) | l3=3: [288,512)
__global__ __launch_bounds__(256) void lin_fused_kernel(
    const __hip_bfloat16* __restrict__ m,
    const float* __restrict__ wl0, const float* __restrict__ wl1,
    const float* __restrict__ wl2, const float* __restrict__ wl3,
    float* __restrict__ out)
{
  __shared__ float A_s[64][65];
  __shared__ float W_s[64][64];
  const int b = blockIdx.x;
  if (b < 32)       lin_body<1, 256, 0>   (b,       m, wl0, out,           A_s, W_s);
  else if (b < 128) lin_body<3, 576, 256> (b - 32,  m, wl1, out + 131072,  A_s, W_s);
  else if (b < 288) lin_body<5, 704, 1984>(b - 128, m, wl2, out + 524288,  A_s, W_s);
  else              lin_body<7, 640, 5504>(b - 288, m, wl3, out + 1179648, A_s, W_s);
}

// ---------------- launch ----------------
extern "C" void kernel_launch(void* const* d_in, const int* in_sizes, int n_in,
                              void* d_out, int out_size, void* d_ws, size_t ws_size,
                              hipStream_t stream) {
  const float* x0  = (const float*)d_in[0];
  const float* y0  = (const float*)d_in[1];
  const float* wl0 = (const float*)d_in[2];
  const float* x1  = (const float*)d_in[3];
  const float* y1  = (const float*)d_in[4];
  const float* wl1 = (const float*)d_in[5];
  const float* x2  = (const float*)d_in[6];
  const float* y2  = (const float*)d_in[7];
  const float* wl2 = (const float*)d_in[8];
  const float* x3  = (const float*)d_in[9];
  const float* y3  = (const float*)d_in[10];
  const float* wl3 = (const float*)d_in[11];
  const float* ws  = (const float*)d_in[12];
  const int* edge_index = (const int*)d_in[13];
  float* out = (float*)d_out;

  __hip_bfloat16* m_i = (__hip_bfloat16*)d_ws;                 // [0, MI_BYTES)
  float* Tbuf = (float*)((char*)d_ws + MI_BYTES);              // [MI_BYTES, +T_BYTES)

  const float* cg_dev;
  if (g_cg_ok) {
    cg_dev = g_cg_dev;
  } else {
    float* cg_ws = (float*)((char*)d_ws + MI_BYTES + T_BYTES);
    hipMemcpyAsync(cg_ws, host_cg, sizeof(host_cg), hipMemcpyHostToDevice, stream);
    cg_dev = cg_ws;
  }

  t_kernel<<<NEDGES, 256, 0, stream>>>(y0, y1, y2, y3, cg_dev, Tbuf);
  tp_node_kernel<<<NNODES, 256, 0, stream>>>(x0, x1, x2, x3, ws, edge_index, Tbuf, m_i);
  lin_fused_kernel<<<512, 256, 0, stream>>>(m_i, wl0, wl1, wl2, wl3, out);
}

// Round 4
// 380.764 us; speedup vs baseline: 2.0553x; 1.2548x over previous
//
#include <hip/hip_runtime.h>
#include <hip/hip_bf16.h>
#include <cmath>
#include <cstdint>

#define NNODES 2048
#define NEDGES 8192
#define NCH 64
#define NHID 64
#define NPATH 34
#define NTASK (NPATH * NCH)   // 2176
#define TTOT 738
#define CGTOT 3436
#define MROW 9984
#define ECAP 128

#define MI_BYTES ((size_t)NNODES * MROW * 2)        // 40,894,464
#define TB_BYTES ((size_t)NEDGES * TTOT * 2)        // 12,091,392 (bf16 T)
#define XT_BYTES ((size_t)NNODES * 16 * NCH * 2)    //  4,194,304 (bf16 xT)

// ---------------- path tables (compile-time) ----------------
struct PathTables {
  int l1[NPATH], l2[NPATH], l3[NPATH];
  int cg_off[NPATH], t_off[NPATH], rank[NPATH];
  unsigned char t_path[TTOT];
  int cg_total, t_total, npaths;
};

constexpr PathTables make_tables() {
  PathTables tb{};
  int np = 0;
  for (int a = 0; a < 4; ++a)
    for (int b = 0; b < 4; ++b) {
      int lo = a > b ? a - b : b - a;
      int hi = a + b < 3 ? a + b : 3;
      for (int c = lo; c <= hi; ++c) { tb.l1[np] = a; tb.l2[np] = b; tb.l3[np] = c; ++np; }
    }
  int cg = 0, tt = 0;
  int cnt[4] = {0, 0, 0, 0};
  for (int i = 0; i < np; ++i) {
    tb.cg_off[i] = cg; tb.t_off[i] = tt; tb.rank[i] = cnt[tb.l3[i]]++;
    int d1 = 2 * tb.l1[i] + 1, d2 = 2 * tb.l2[i] + 1, d3 = 2 * tb.l3[i] + 1;
    cg += d1 * d2 * d3;
    for (int k = 0; k < d1 * d3; ++k) tb.t_path[tt + k] = (unsigned char)i;
    tt += d1 * d3;
  }
  tb.cg_total = cg; tb.t_total = tt; tb.npaths = np;
  return tb;
}

constexpr PathTables H_TB = make_tables();
static_assert(H_TB.npaths == NPATH, "npaths");
static_assert(H_TB.cg_total == CGTOT, "cgtot");
static_assert(H_TB.t_total == TTOT, "ttot");

__constant__ PathTables d_tb = make_tables();

// ---------------- NumPy legacy RandomState(1234) reproduction (host) ----------------
namespace {
struct MT19937 {
  uint32_t mt[624]; int mti; bool has_g; double gval;
  void seed(uint32_t s) {
    for (int i = 0; i < 624; ++i) { mt[i] = s; s = 1812433253u * (s ^ (s >> 30)) + (uint32_t)i + 1u; }
    mti = 624; has_g = false; gval = 0.0;
  }
  uint32_t next() {
    if (mti >= 624) {
      for (int i = 0; i < 624; ++i) {
        uint32_t y = (mt[i] & 0x80000000u) | (mt[(i + 1) % 624] & 0x7fffffffu);
        mt[i] = mt[(i + 397) % 624] ^ (y >> 1) ^ ((y & 1u) ? 0x9908b0dfu : 0u);
      }
      mti = 0;
    }
    uint32_t y = mt[mti++];
    y ^= y >> 11; y ^= (y << 7) & 0x9d2c5680u; y ^= (y << 15) & 0xefc60000u; y ^= y >> 18;
    return y;
  }
  double rdbl() {
    uint32_t a = next() >> 5, b = next() >> 6;
    return ((double)a * 67108864.0 + (double)b) / 9007199254740992.0;
  }
  double gauss() {
    if (has_g) { has_g = false; return gval; }
    double x1, x2, r2;
    do {
      x1 = 2.0 * rdbl() - 1.0;
      x2 = 2.0 * rdbl() - 1.0;
      r2 = x1 * x1 + x2 * x2;
    } while (r2 >= 1.0 || r2 == 0.0);
    double f = std::sqrt(-2.0 * std::log(r2) / r2);
    gval = f * x1; has_g = true;
    return f * x2;
  }
};

float host_cg[CGTOT];
float* g_cg_dev = nullptr;
bool g_cg_ok = false;

struct CGInit {
  CGInit() {
    MT19937 g; g.seed(1234u);
    int idx = 0;
    for (int i = 0; i < NPATH; ++i) {
      int d1 = 2 * H_TB.l1[i] + 1, d2 = 2 * H_TB.l2[i] + 1, d3 = 2 * H_TB.l3[i] + 1;
      int sz = d1 * d2 * d3;
      for (int k = 0; k < sz; ++k) host_cg[idx++] = (float)(g.gauss() * 0.2);
    }
    (void)hipHostRegister(host_cg, sizeof(host_cg), hipHostRegisterDefault);  // fast fallback H2D
    void* p = nullptr;
    if (hipMalloc(&p, sizeof(host_cg)) == hipSuccess && p) {
      if (hipMemcpy(p, host_cg, sizeof(host_cg), hipMemcpyHostToDevice) == hipSuccess) {
        float back = 0.f;
        if (hipMemcpy(&back, (float*)p + (CGTOT - 1), sizeof(float),
                      hipMemcpyDeviceToHost) == hipSuccess && back == host_cg[CGTOT - 1]) {
          g_cg_dev = (float*)p;
          g_cg_ok = true;
        }
      }
    }
  }
} cg_init_instance;
}  // namespace

__device__ __forceinline__ float bf2f(unsigned short u) {
  union { unsigned int i; float f; } v; v.i = ((unsigned int)u) << 16; return v.f;
}

// ---------------- kernel 0: prep — per-edge T (bf16) + per-node xT (bf16) ----------------
__global__ __launch_bounds__(256) void prep_kernel(
    const float* __restrict__ y0, const float* __restrict__ y1,
    const float* __restrict__ y2, const float* __restrict__ y3,
    const float* __restrict__ x0, const float* __restrict__ x1,
    const float* __restrict__ x2, const float* __restrict__ x3,
    const float* __restrict__ cg_g,
    __hip_bfloat16* __restrict__ Tbuf, __hip_bfloat16* __restrict__ xT)
{
  const int b = blockIdx.x;
  const int t = threadIdx.x;
  if (b < NEDGES) {
    __shared__ float y_s[16];
    const int e = b;
    if (t < 16) {
      float v;
      if (t < 1)      v = y0[e];
      else if (t < 4) v = y1[e * 3 + (t - 1)];
      else if (t < 9) v = y2[e * 5 + (t - 4)];
      else            v = y3[e * 7 + (t - 9)];
      y_s[t] = v;
    }
    __syncthreads();
    constexpr int ybase[4] = {0, 1, 4, 9};
    __hip_bfloat16* To = Tbuf + (size_t)e * TTOT;
    for (int tt = t; tt < TTOT; tt += 256) {
      const int i   = d_tb.t_path[tt];
      const int l2v = d_tb.l2[i], l3v = d_tb.l3[i];
      const int d2  = 2 * l2v + 1, d3 = 2 * l3v + 1;
      const int local = tt - d_tb.t_off[i];
      const int l   = local / d3;
      const int n3  = local - l * d3;
      const float* cg = cg_g + d_tb.cg_off[i] + l * d2 * d3 + n3;
      float acc = 0.f;
      for (int m = 0; m < d2; ++m) acc += cg[m * d3] * y_s[ybase[l2v] + m];
      To[tt] = __float2bfloat16(acc);
    }
  } else {
    const int n = b - NEDGES;
    for (int idx = t; idx < 1024; idx += 256) {
      const int j = idx >> 6, c = idx & 63;   // j wave-uniform
      const float* src; int d1, m;
      if (j < 1)      { src = x0; d1 = 1; m = j; }
      else if (j < 4) { src = x1; d1 = 3; m = j - 1; }
      else if (j < 9) { src = x2; d1 = 5; m = j - 4; }
      else            { src = x3; d1 = 7; m = j - 9; }
      const float v = src[((size_t)n * NCH + c) * d1 + m];
      xT[((size_t)n * 16 + j) * NCH + c] = __float2bfloat16(v);
    }
  }
}

// ---------------- kernel 1: per-node TP, exact-shape tasks ----------------
template <int D1, int D3>
__device__ __forceinline__ void tp_task_run(
    int task, int toff, int rank, int cnt,
    const int* __restrict__ elist, const int* __restrict__ esrc,
    const __hip_bfloat16* __restrict__ xT,
    const __hip_bfloat16* __restrict__ Tbuf,
    const float* __restrict__ ws,
    int n, __hip_bfloat16* __restrict__ m_out)
{
  constexpr int Kc = (D3 == 1) ? 256 : (D3 == 3) ? 576 : (D3 == 5) ? 704 : 640;
  constexpr int Rc = (D3 == 1) ? 0 : (D3 == 3) ? 256 : (D3 == 5) ? 1984 : 5504;
  constexpr int JB = (D1 == 1) ? 0 : (D1 == 3) ? 1 : (D1 == 5) ? 4 : 9;
  const int c = task & 63;

  float acc[D3];
#pragma unroll
  for (int m = 0; m < D3; ++m) acc[m] = 0.f;

  for (int ei = 0; ei < cnt; ++ei) {
    const int e = __builtin_amdgcn_readfirstlane(elist[ei]);
    const int s = __builtin_amdgcn_readfirstlane(esrc[ei]);
    const float w = ws[(size_t)e * NTASK + task];                       // coalesced
    const __hip_bfloat16* __restrict__ Tp = Tbuf + (size_t)e * TTOT + toff;  // broadcast
    const __hip_bfloat16* __restrict__ xr = xT + ((size_t)s * 16 + JB) * NCH + c;  // coalesced
    float u[D3];
#pragma unroll
    for (int m = 0; m < D3; ++m) u[m] = 0.f;
#pragma unroll
    for (int l = 0; l < D1; ++l) {
      const float xv = __bfloat162float(xr[l * NCH]);
#pragma unroll
      for (int m = 0; m < D3; ++m)
        u[m] += xv * __bfloat162float(Tp[l * D3 + m]);
    }
#pragma unroll
    for (int m = 0; m < D3; ++m) acc[m] += w * u[m];
  }

  __hip_bfloat16* mo = m_out + (size_t)n * MROW + Rc + rank * NCH + c;
#pragma unroll
  for (int m = 0; m < D3; ++m) mo[m * Kc] = __float2bfloat16(acc[m]);   // coalesced
}

__global__ __launch_bounds__(256) void tp_node_kernel(
    const float* __restrict__ ws, const int* __restrict__ edge_index,
    const __hip_bfloat16* __restrict__ xT,
    const __hip_bfloat16* __restrict__ Tbuf,
    __hip_bfloat16* __restrict__ m_out)
{
  __shared__ int elist[ECAP];
  __shared__ int esrc[ECAP];
  __shared__ int ecount;

  const int n = blockIdx.x;
  const int t = threadIdx.x;
  if (t == 0) ecount = 0;
  __syncthreads();

  const int* __restrict__ srcs = edge_index;
  const int4* __restrict__ d4 = (const int4*)(edge_index + NEDGES);
  for (int q = t; q < NEDGES / 4; q += 256) {
    const int4 v = d4[q];
    const int e0 = q * 4;
    if (v.x == n) { int p = atomicAdd(&ecount, 1); if (p < ECAP) elist[p] = e0; }
    if (v.y == n) { int p = atomicAdd(&ecount, 1); if (p < ECAP) elist[p] = e0 + 1; }
    if (v.z == n) { int p = atomicAdd(&ecount, 1); if (p < ECAP) elist[p] = e0 + 2; }
    if (v.w == n) { int p = atomicAdd(&ecount, 1); if (p < ECAP) elist[p] = e0 + 3; }
  }
  __syncthreads();
  const int cnt = ecount < ECAP ? ecount : ECAP;
  if (t < cnt) esrc[t] = srcs[elist[t]];
  __syncthreads();

  for (int k = 0; t + k * 256 < NTASK; ++k) {
    const int task = t + k * 256;
    const int i = task >> 6;                 // wave-uniform
    const int toff = d_tb.t_off[i];
    const int rk = d_tb.rank[i];
    const int code = d_tb.l1[i] * 4 + d_tb.l3[i];
    switch (code) {
      case  0: tp_task_run<1,1>(task, toff, rk, cnt, elist, esrc, xT, Tbuf, ws, n, m_out); break;
      case  1: tp_task_run<1,3>(task, toff, rk, cnt, elist, esrc, xT, Tbuf, ws, n, m_out); break;
      case  2: tp_task_run<1,5>(task, toff, rk, cnt, elist, esrc, xT, Tbuf, ws, n, m_out); break;
      case  3: tp_task_run<1,7>(task, toff, rk, cnt, elist, esrc, xT, Tbuf, ws, n, m_out); break;
      case  4: tp_task_run<3,1>(task, toff, rk, cnt, elist, esrc, xT, Tbuf, ws, n, m_out); break;
      case  5: tp_task_run<3,3>(task, toff, rk, cnt, elist, esrc, xT, Tbuf, ws, n, m_out); break;
      case  6: tp_task_run<3,5>(task, toff, rk, cnt, elist, esrc, xT, Tbuf, ws, n, m_out); break;
      case  7: tp_task_run<3,7>(task, toff, rk, cnt, elist, esrc, xT, Tbuf, ws, n, m_out); break;
      case  8: tp_task_run<5,1>(task, toff, rk, cnt, elist, esrc, xT, Tbuf, ws, n, m_out); break;
      case  9: tp_task_run<5,3>(task, toff, rk, cnt, elist, esrc, xT, Tbuf, ws, n, m_out); break;
      case 10: tp_task_run<5,5>(task, toff, rk, cnt, elist, esrc, xT, Tbuf, ws, n, m_out); break;
      case 11: tp_task_run<5,7>(task, toff, rk, cnt, elist, esrc, xT, Tbuf, ws, n, m_out); break;
      case 12: tp_task_run<7,1>(task, toff, rk, cnt, elist, esrc, xT, Tbuf, ws, n, m_out); break;
      case 13: tp_task_run<7,3>(task, toff, rk, cnt, elist, esrc, xT, Tbuf, ws, n, m_out); break;
      case 14: tp_task_run<7,5>(task, toff, rk, cnt, elist, esrc, xT, Tbuf, ws, n, m_out); break;
      default: tp_task_run<7,7>(task, toff, rk, cnt, elist, esrc, xT, Tbuf, ws, n, m_out); break;
    }
  }
}

// ---------------- kernel 2: fused per-l3 linear ----------------
template <int D3, int K, int ROFF>
__device__ __forceinline__ void lin_body(
    int blk, const __hip_bfloat16* __restrict__ m, const float* __restrict__ wl,
    float* __restrict__ out, float (*A_s)[65], float (*W_s)[64])
{
  const unsigned short* __restrict__ mu = (const unsigned short*)m;
  const int t  = threadIdx.x;
  const int r0 = blk * 64;
  const int hq = t & 15;
  const int rq = t >> 4;
  float acc[4][4] = {};

  for (int k0 = 0; k0 < K; k0 += 64) {
    for (int idx = t; idx < 1024; idx += 256) {          // W: float4 fills
      const int kk = idx >> 4, h4 = (idx & 15) * 4;
      *(float4*)&W_s[kk][h4] = *(const float4*)(wl + (size_t)(k0 + kk) * 64 + h4);
    }
    for (int idx = t; idx < 1024; idx += 256) {          // A: ushort4 fills
      const int rr = idx >> 4, kq = (idx & 15) * 4;
      const int r = r0 + rr;
      const int nn = r / D3, mm = r - nn * D3;
      const ushort4 p = *(const ushort4*)(mu + (size_t)nn * MROW + ROFF + mm * K + k0 + kq);
      A_s[rr][kq + 0] = bf2f(p.x);
      A_s[rr][kq + 1] = bf2f(p.y);
      A_s[rr][kq + 2] = bf2f(p.z);
      A_s[rr][kq + 3] = bf2f(p.w);
    }
    __syncthreads();
#pragma unroll
    for (int kk = 0; kk < 64; ++kk) {
      const float4 wv = *(const float4*)(&W_s[kk][hq * 4]);
#pragma unroll
      for (int i2 = 0; i2 < 4; ++i2) {
        const float a = A_s[rq * 4 + i2][kk];
        acc[i2][0] += a * wv.x;
        acc[i2][1] += a * wv.y;
        acc[i2][2] += a * wv.z;
        acc[i2][3] += a * wv.w;
      }
    }
    __syncthreads();
  }

#pragma unroll
  for (int i2 = 0; i2 < 4; ++i2) {
    const int r = r0 + rq * 4 + i2;
    const int nn = r / D3, mm = r - nn * D3;
#pragma unroll
    for (int j = 0; j < 4; ++j)
      out[((size_t)nn * NHID + hq * 4 + j) * D3 + mm] = acc[i2][j];
  }
}

__global__ __launch_bounds__(256) void lin_fused_kernel(
    const __hip_bfloat16* __restrict__ m,
    const float* __restrict__ wl0, const float* __restrict__ wl1,
    const float* __restrict__ wl2, const float* __restrict__ wl3,
    float* __restrict__ out)
{
  __shared__ float A_s[64][65];
  __shared__ float W_s[64][64];
  const int b = blockIdx.x;
  if (b < 32)       lin_body<1, 256, 0>   (b,       m, wl0, out,           A_s, W_s);
  else if (b < 128) lin_body<3, 576, 256> (b - 32,  m, wl1, out + 131072,  A_s, W_s);
  else if (b < 288) lin_body<5, 704, 1984>(b - 128, m, wl2, out + 524288,  A_s, W_s);
  else              lin_body<7, 640, 5504>(b - 288, m, wl3, out + 1179648, A_s, W_s);
}

// ---------------- launch ----------------
extern "C" void kernel_launch(void* const* d_in, const int* in_sizes, int n_in,
                              void* d_out, int out_size, void* d_ws, size_t ws_size,
                              hipStream_t stream) {
  const float* x0  = (const float*)d_in[0];
  const float* y0  = (const float*)d_in[1];
  const float* wl0 = (const float*)d_in[2];
  const float* x1  = (const float*)d_in[3];
  const float* y1  = (const float*)d_in[4];
  const float* wl1 = (const float*)d_in[5];
  const float* x2  = (const float*)d_in[6];
  const float* y2  = (const float*)d_in[7];
  const float* wl2 = (const float*)d_in[8];
  const float* x3  = (const float*)d_in[9];
  const float* y3  = (const float*)d_in[10];
  const float* wl3 = (const float*)d_in[11];
  const float* ws  = (const float*)d_in[12];
  const int* edge_index = (const int*)d_in[13];
  float* out = (float*)d_out;

  __hip_bfloat16* m_i  = (__hip_bfloat16*)d_ws;
  __hip_bfloat16* Tbuf = (__hip_bfloat16*)((char*)d_ws + MI_BYTES);
  __hip_bfloat16* xT   = (__hip_bfloat16*)((char*)d_ws + MI_BYTES + TB_BYTES);

  const float* cg_dev;
  if (g_cg_ok) {
    cg_dev = g_cg_dev;
  } else {
    float* cg_ws = (float*)((char*)d_ws + MI_BYTES + TB_BYTES + XT_BYTES);
    hipMemcpyAsync(cg_ws, host_cg, sizeof(host_cg), hipMemcpyHostToDevice, stream);
    cg_dev = cg_ws;
  }

  prep_kernel<<<NEDGES + NNODES, 256, 0, stream>>>(y0, y1, y2, y3, x0, x1, x2, x3,
                                                   cg_dev, Tbuf, xT);
  tp_node_kernel<<<NNODES, 256, 0, stream>>>(ws, edge_index, xT, Tbuf, m_i);
  lin_fused_kernel<<<512, 256, 0, stream>>>(m_i, wl0, wl1, wl2, wl3, out);
}

// Round 5
// 330.480 us; speedup vs baseline: 2.3680x; 1.1522x over previous
//
#include <hip/hip_runtime.h>
#include <hip/hip_bf16.h>
#include <cmath>
#include <cstdint>

#define NNODES 2048
#define NEDGES 8192
#define NCH 64
#define NHID 64
#define NPATH 34
#define NTASK (NPATH * NCH)   // 2176
#define CGTOT 3436
#define MROW 9984
#define TTOT2 888             // per-edge T row, per-path 8-aligned
#define EBLK 5                // edges staged in LDS per chunk

#define MI_BYTES ((size_t)NNODES * MROW * 2)          // 40,894,464
#define TB_BYTES ((size_t)NEDGES * TTOT2 * 2)         // 14,548,992
#define XT_BYTES ((size_t)NNODES * 16 * NCH * 2)      //  4,194,304
#define OFF_OFF  (MI_BYTES + TB_BYTES + XT_BYTES)     // csr_off: 2049 ints (pad 2052)
#define CUR_OFF  (OFF_OFF + 2052 * 4)
#define PACK_OFF (CUR_OFF + 2048 * 4)
#define CGP_OFF  (PACK_OFF + 8192 * 4)
#define CGP_FLOATS (TTOT2 * 9)                        // 888*8 CGT2 + 888 meta

// ---------------- path tables (compile-time) ----------------
struct PathTables {
  int l1[NPATH], l2[NPATH], l3[NPATH];
  int cg_off[NPATH], t_off2[NPATH], rank[NPATH];
  int cg_total, ttot2, npaths;
};

constexpr PathTables make_tables() {
  PathTables tb{};
  int np = 0;
  for (int a = 0; a < 4; ++a)
    for (int b = 0; b < 4; ++b) {
      int lo = a > b ? a - b : b - a;
      int hi = a + b < 3 ? a + b : 3;
      for (int c = lo; c <= hi; ++c) { tb.l1[np] = a; tb.l2[np] = b; tb.l3[np] = c; ++np; }
    }
  int cg = 0, tt2 = 0;
  int cnt[4] = {0, 0, 0, 0};
  for (int i = 0; i < np; ++i) {
    tb.cg_off[i] = cg; tb.t_off2[i] = tt2; tb.rank[i] = cnt[tb.l3[i]]++;
    int d1 = 2 * tb.l1[i] + 1, d3 = 2 * tb.l3[i] + 1;
    cg += d1 * (2 * tb.l2[i] + 1) * d3;
    tt2 += ((d1 * d3 + 7) / 8) * 8;
  }
  tb.cg_total = cg; tb.ttot2 = tt2; tb.npaths = np;
  return tb;
}

constexpr PathTables H_TB = make_tables();
static_assert(H_TB.npaths == NPATH, "npaths");
static_assert(H_TB.cg_total == CGTOT, "cgtot");
static_assert(H_TB.ttot2 == TTOT2, "ttot2");

__constant__ PathTables d_tb = make_tables();

// ---------------- NumPy legacy RandomState(1234) reproduction (host) ----------------
namespace {
struct MT19937 {
  uint32_t mt[624]; int mti; bool has_g; double gval;
  void seed(uint32_t s) {
    for (int i = 0; i < 624; ++i) { mt[i] = s; s = 1812433253u * (s ^ (s >> 30)) + (uint32_t)i + 1u; }
    mti = 624; has_g = false; gval = 0.0;
  }
  uint32_t next() {
    if (mti >= 624) {
      for (int i = 0; i < 624; ++i) {
        uint32_t y = (mt[i] & 0x80000000u) | (mt[(i + 1) % 624] & 0x7fffffffu);
        mt[i] = mt[(i + 397) % 624] ^ (y >> 1) ^ ((y & 1u) ? 0x9908b0dfu : 0u);
      }
      mti = 0;
    }
    uint32_t y = mt[mti++];
    y ^= y >> 11; y ^= (y << 7) & 0x9d2c5680u; y ^= (y << 15) & 0xefc60000u; y ^= y >> 18;
    return y;
  }
  double rdbl() {
    uint32_t a = next() >> 5, b = next() >> 6;
    return ((double)a * 67108864.0 + (double)b) / 9007199254740992.0;
  }
  double gauss() {
    if (has_g) { has_g = false; return gval; }
    double x1, x2, r2;
    do {
      x1 = 2.0 * rdbl() - 1.0;
      x2 = 2.0 * rdbl() - 1.0;
      r2 = x1 * x1 + x2 * x2;
    } while (r2 >= 1.0 || r2 == 0.0);
    double f = std::sqrt(-2.0 * std::log(r2) / r2);
    gval = f * x1; has_g = true;
    return f * x2;
  }
};

float host_pack[CGP_FLOATS];   // [888*8] CGT2 rows + [888] ybase-as-float
float* g_cg_dev = nullptr;
bool g_cg_ok = false;

struct CGInit {
  CGInit() {
    static float cg[CGTOT];
    MT19937 g; g.seed(1234u);
    int idx = 0;
    for (int i = 0; i < NPATH; ++i) {
      int d1 = 2 * H_TB.l1[i] + 1, d2 = 2 * H_TB.l2[i] + 1, d3 = 2 * H_TB.l3[i] + 1;
      int sz = d1 * d2 * d3;
      for (int k = 0; k < sz; ++k) cg[idx++] = (float)(g.gauss() * 0.2);
    }
    const int ybase[4] = {0, 1, 4, 9};
    for (int k = 0; k < CGP_FLOATS; ++k) host_pack[k] = 0.f;
    for (int i = 0; i < NPATH; ++i) {
      int d1 = 2 * H_TB.l1[i] + 1, d2 = 2 * H_TB.l2[i] + 1, d3 = 2 * H_TB.l3[i] + 1;
      for (int l = 0; l < d1; ++l)
        for (int n3 = 0; n3 < d3; ++n3) {
          int tt2 = H_TB.t_off2[i] + l * d3 + n3;
          for (int m = 0; m < d2; ++m)
            host_pack[tt2 * 8 + m] = cg[H_TB.cg_off[i] + l * d2 * d3 + m * d3 + n3];
          host_pack[TTOT2 * 8 + tt2] = (float)ybase[H_TB.l2[i]];
        }
    }
    (void)hipHostRegister(host_pack, sizeof(host_pack), hipHostRegisterDefault);
    void* p = nullptr;
    if (hipMalloc(&p, sizeof(host_pack)) == hipSuccess && p) {
      if (hipMemcpy(p, host_pack, sizeof(host_pack), hipMemcpyHostToDevice) == hipSuccess) {
        float back = -1.f;
        if (hipMemcpy(&back, (float*)p + (CGP_FLOATS - 1), sizeof(float),
                      hipMemcpyDeviceToHost) == hipSuccess && back == host_pack[CGP_FLOATS - 1]) {
          g_cg_dev = (float*)p;
          g_cg_ok = true;
        }
      }
    }
  }
} cg_init_instance;
}  // namespace

__device__ __forceinline__ float bf2f(unsigned short u) {
  union { unsigned int i; float f; } v; v.i = ((unsigned int)u) << 16; return v.f;
}

// ---------------- kernel 0: prep — per-edge T (bf16, CGT2 layout) + per-node xT ----------------
__global__ __launch_bounds__(256) void prep_kernel(
    const float* __restrict__ y0, const float* __restrict__ y1,
    const float* __restrict__ y2, const float* __restrict__ y3,
    const float* __restrict__ x0, const float* __restrict__ x1,
    const float* __restrict__ x2, const float* __restrict__ x3,
    const float* __restrict__ cg_pack,
    __hip_bfloat16* __restrict__ Tbuf, __hip_bfloat16* __restrict__ xT)
{
  const int b = blockIdx.x;
  const int t = threadIdx.x;
  if (b < NEDGES) {
    __shared__ float y_s[17];
    const int e = b;
    if (t == 16) y_s[16] = 0.f;
    if (t < 16) {
      float v;
      if (t < 1)      v = y0[e];
      else if (t < 4) v = y1[e * 3 + (t - 1)];
      else if (t < 9) v = y2[e * 5 + (t - 4)];
      else            v = y3[e * 7 + (t - 9)];
      y_s[t] = v;
    }
    __syncthreads();
    const float* __restrict__ metaf = cg_pack + TTOT2 * 8;
    __hip_bfloat16* To = Tbuf + (size_t)e * TTOT2;
    for (int tt2 = t; tt2 < TTOT2; tt2 += 256) {
      const float4 a = *(const float4*)(cg_pack + tt2 * 8);
      const float4 c = *(const float4*)(cg_pack + tt2 * 8 + 4);
      const int yb = (int)metaf[tt2];
      float acc = a.x * y_s[yb]     + a.y * y_s[yb + 1] + a.z * y_s[yb + 2] + a.w * y_s[yb + 3]
                + c.x * y_s[yb + 4] + c.y * y_s[yb + 5] + c.z * y_s[yb + 6] + c.w * y_s[yb + 7];
      To[tt2] = __float2bfloat16(acc);
    }
  } else {
    const int n = b - NEDGES;
    for (int idx = t; idx < 1024; idx += 256) {
      const int j = idx >> 6, c = idx & 63;   // j wave-uniform
      const float* src; int d1, m;
      if (j < 1)      { src = x0; d1 = 1; m = j; }
      else if (j < 4) { src = x1; d1 = 3; m = j - 1; }
      else if (j < 9) { src = x2; d1 = 5; m = j - 4; }
      else            { src = x3; d1 = 7; m = j - 9; }
      const float v = src[((size_t)n * NCH + c) * d1 + m];
      xT[((size_t)n * 16 + j) * NCH + c] = __float2bfloat16(v);
    }
  }
}

// ---------------- kernel 0b/0c: CSR build ----------------
__global__ __launch_bounds__(256) void scan_kernel(
    const int* __restrict__ edge_index, int* __restrict__ off, int* __restrict__ cursor)
{
  __shared__ int ldeg[NNODES];
  __shared__ int csum[256];
  const int t = threadIdx.x;
  for (int i = t; i < NNODES; i += 256) ldeg[i] = 0;
  __syncthreads();
  const int* __restrict__ dsts = edge_index + NEDGES;
  for (int e = t; e < NEDGES; e += 256) atomicAdd(&ldeg[dsts[e]], 1);
  __syncthreads();
  int loc[8], s = 0;
  const int base0 = t * 8;
#pragma unroll
  for (int j = 0; j < 8; ++j) { loc[j] = ldeg[base0 + j]; s += loc[j]; }
  csum[t] = s;
  __syncthreads();
  for (int o = 1; o < 256; o <<= 1) {
    int v = (t >= o) ? csum[t - o] : 0;
    __syncthreads();
    csum[t] += v;
    __syncthreads();
  }
  int run = csum[t] - s;
#pragma unroll
  for (int j = 0; j < 8; ++j) { off[base0 + j] = run; cursor[base0 + j] = run; run += loc[j]; }
  if (t == 0) off[NNODES] = NEDGES;
}

__global__ __launch_bounds__(256) void fill_kernel(
    const int* __restrict__ edge_index, int* __restrict__ cursor, int* __restrict__ pack)
{
  const int e = blockIdx.x * 256 + threadIdx.x;
  if (e >= NEDGES) return;
  const int d = edge_index[NEDGES + e];
  const int s = edge_index[e];
  const int pos = atomicAdd(&cursor[d], 1);
  pack[pos] = e | (s << 13);
}

// ---------------- kernel 1: per-node TP, LDS-staged T ----------------
template <int D1, int D3>
__device__ __forceinline__ void tp_task_run(
    int task, int toff2, int rank, int nb, const int* __restrict__ epk,
    const float (*Ts)[TTOT2], const float* __restrict__ ws,
    const unsigned short* __restrict__ xT,
    int n, bool first, __hip_bfloat16* __restrict__ m_out)
{
  constexpr int Kc = (D3 == 1) ? 256 : (D3 == 3) ? 576 : (D3 == 5) ? 704 : 640;
  constexpr int Rc = (D3 == 1) ? 0 : (D3 == 3) ? 256 : (D3 == 5) ? 1984 : 5504;
  constexpr int JB = (D1 == 1) ? 0 : (D1 == 3) ? 1 : (D1 == 5) ? 4 : 9;
  const int c = task & 63;

  float acc[D3];
#pragma unroll
  for (int m = 0; m < D3; ++m) acc[m] = 0.f;

  for (int ei = 0; ei < nb; ++ei) {
    const int pk = epk[ei];
    const int e = pk & 8191;
    const int s = pk >> 13;
    const float w = ws[(size_t)e * NTASK + task];                    // coalesced
    const unsigned short* __restrict__ xr = xT + ((size_t)s * 16 + JB) * NCH + c;  // coalesced
    const float* __restrict__ Tp = &Ts[ei][toff2];                   // LDS broadcast
    float u[D3];
#pragma unroll
    for (int m = 0; m < D3; ++m) u[m] = 0.f;
#pragma unroll
    for (int l = 0; l < D1; ++l) {
      const float xv = bf2f(xr[l * NCH]);
#pragma unroll
      for (int m = 0; m < D3; ++m) u[m] += xv * Tp[l * D3 + m];
    }
#pragma unroll
    for (int m = 0; m < D3; ++m) acc[m] += w * u[m];
  }

  __hip_bfloat16* mo = m_out + (size_t)n * MROW + Rc + rank * NCH + c;
  if (first) {
#pragma unroll
    for (int m = 0; m < D3; ++m) mo[m * Kc] = __float2bfloat16(acc[m]);
  } else {
#pragma unroll
    for (int m = 0; m < D3; ++m)
      mo[m * Kc] = __float2bfloat16(__bfloat162float(mo[m * Kc]) + acc[m]);
  }
}

__global__ __launch_bounds__(256) void tp_node_kernel(
    const float* __restrict__ ws, const unsigned short* __restrict__ xT,
    const unsigned short* __restrict__ Tbuf,
    const int* __restrict__ off, const int* __restrict__ pack,
    __hip_bfloat16* __restrict__ m_out)
{
  __shared__ float Ts[EBLK][TTOT2];   // 17.76 KB
  __shared__ int epk[EBLK];

  const int n = blockIdx.x;
  const int t = threadIdx.x;
  const int beg = off[n];
  const int cnt = off[n + 1] - beg;

  for (int base = 0; base == 0 || base < cnt; base += EBLK) {
    int nb = cnt - base;
    nb = nb < 0 ? 0 : (nb > EBLK ? EBLK : nb);
    if (t < nb) epk[t] = pack[beg + base + t];
    __syncthreads();
    for (int ei = 0; ei < nb; ++ei) {
      const unsigned int* __restrict__ src =
          (const unsigned int*)Tbuf + (size_t)(epk[ei] & 8191) * (TTOT2 / 2);
      for (int j = t; j < TTOT2 / 2; j += 256) {
        const unsigned int v = src[j];
        Ts[ei][2 * j]     = bf2f((unsigned short)(v & 0xffffu));
        Ts[ei][2 * j + 1] = bf2f((unsigned short)(v >> 16));
      }
    }
    __syncthreads();

    const bool first = (base == 0);
    for (int k = 0; k * 256 + t < NTASK; ++k) {
      const int task = k * 256 + t;
      const int i = task >> 6;                 // wave-uniform
      const int toff2 = d_tb.t_off2[i];
      const int rk = d_tb.rank[i];
      const int code = d_tb.l1[i] * 4 + d_tb.l3[i];
      switch (code) {
        case  0: tp_task_run<1,1>(task, toff2, rk, nb, epk, Ts, ws, xT, n, first, m_out); break;
        case  1: tp_task_run<1,3>(task, toff2, rk, nb, epk, Ts, ws, xT, n, first, m_out); break;
        case  2: tp_task_run<1,5>(task, toff2, rk, nb, epk, Ts, ws, xT, n, first, m_out); break;
        case  3: tp_task_run<1,7>(task, toff2, rk, nb, epk, Ts, ws, xT, n, first, m_out); break;
        case  4: tp_task_run<3,1>(task, toff2, rk, nb, epk, Ts, ws, xT, n, first, m_out); break;
        case  5: tp_task_run<3,3>(task, toff2, rk, nb, epk, Ts, ws, xT, n, first, m_out); break;
        case  6: tp_task_run<3,5>(task, toff2, rk, nb, epk, Ts, ws, xT, n, first, m_out); break;
        case  7: tp_task_run<3,7>(task, toff2, rk, nb, epk, Ts, ws, xT, n, first, m_out); break;
        case  8: tp_task_run<5,1>(task, toff2, rk, nb, epk, Ts, ws, xT, n, first, m_out); break;
        case  9: tp_task_run<5,3>(task, toff2, rk, nb, epk, Ts, ws, xT, n, first, m_out); break;
        case 10: tp_task_run<5,5>(task, toff2, rk, nb, epk, Ts, ws, xT, n, first, m_out); break;
        case 11: tp_task_run<5,7>(task, toff2, rk, nb, epk, Ts, ws, xT, n, first, m_out); break;
        case 12: tp_task_run<7,1>(task, toff2, rk, nb, epk, Ts, ws, xT, n, first, m_out); break;
        case 13: tp_task_run<7,3>(task, toff2, rk, nb, epk, Ts, ws, xT, n, first, m_out); break;
        case 14: tp_task_run<7,5>(task, toff2, rk, nb, epk, Ts, ws, xT, n, first, m_out); break;
        default: tp_task_run<7,7>(task, toff2, rk, nb, epk, Ts, ws, xT, n, first, m_out); break;
      }
    }
    __syncthreads();
  }
}

// ---------------- kernel 2: fused per-l3 linear (32-row tiles, 1024 blocks) ----------------
template <int D3, int K, int ROFF>
__device__ __forceinline__ void lin_body(
    int blk, const unsigned short* __restrict__ mu, const float* __restrict__ wl,
    float* __restrict__ out, float (*A_s)[65], float (*W_s)[64])
{
  const int t  = threadIdx.x;
  const int r0 = blk * 32;
  const int hq = t & 15;
  const int rq = t >> 4;
  float acc[2][4] = {};

  for (int k0 = 0; k0 < K; k0 += 64) {
    for (int idx = t; idx < 1024; idx += 256) {
      const int kk = idx >> 4, h4 = (idx & 15) * 4;
      *(float4*)&W_s[kk][h4] = *(const float4*)(wl + (size_t)(k0 + kk) * 64 + h4);
    }
    for (int idx = t; idx < 512; idx += 256) {
      const int rr = idx >> 4, kq = (idx & 15) * 4;
      const int r = r0 + rr;
      const int nn = r / D3, mm = r - nn * D3;
      const ushort4 p = *(const ushort4*)(mu + (size_t)nn * MROW + ROFF + mm * K + k0 + kq);
      A_s[rr][kq + 0] = bf2f(p.x);
      A_s[rr][kq + 1] = bf2f(p.y);
      A_s[rr][kq + 2] = bf2f(p.z);
      A_s[rr][kq + 3] = bf2f(p.w);
    }
    __syncthreads();
#pragma unroll
    for (int kk = 0; kk < 64; ++kk) {
      const float4 wv = *(const float4*)(&W_s[kk][hq * 4]);
#pragma unroll
      for (int i2 = 0; i2 < 2; ++i2) {
        const float a = A_s[rq * 2 + i2][kk];
        acc[i2][0] += a * wv.x;
        acc[i2][1] += a * wv.y;
        acc[i2][2] += a * wv.z;
        acc[i2][3] += a * wv.w;
      }
    }
    __syncthreads();
  }

#pragma unroll
  for (int i2 = 0; i2 < 2; ++i2) {
    const int r = r0 + rq * 2 + i2;
    const int nn = r / D3, mm = r - nn * D3;
#pragma unroll
    for (int j = 0; j < 4; ++j)
      out[((size_t)nn * NHID + hq * 4 + j) * D3 + mm] = acc[i2][j];
  }
}

// segments (32-row tiles): l3=0: [0,64) | l3=1: [64,256) | l3=2: [256,576) | l3=3: [576,1024)
__global__ __launch_bounds__(256) void lin_fused_kernel(
    const unsigned short* __restrict__ mu,
    const float* __restrict__ wl0, const float* __restrict__ wl1,
    const float* __restrict__ wl2, const float* __restrict__ wl3,
    float* __restrict__ out)
{
  __shared__ float A_s[32][65];
  __shared__ float W_s[64][64];
  const int b = blockIdx.x;
  if (b < 64)       lin_body<1, 256, 0>   (b,       mu, wl0, out,           A_s, W_s);
  else if (b < 256) lin_body<3, 576, 256> (b - 64,  mu, wl1, out + 131072,  A_s, W_s);
  else if (b < 576) lin_body<5, 704, 1984>(b - 256, mu, wl2, out + 524288,  A_s, W_s);
  else              lin_body<7, 640, 5504>(b - 576, mu, wl3, out + 1179648, A_s, W_s);
}

// ---------------- launch ----------------
extern "C" void kernel_launch(void* const* d_in, const int* in_sizes, int n_in,
                              void* d_out, int out_size, void* d_ws, size_t ws_size,
                              hipStream_t stream) {
  const float* x0  = (const float*)d_in[0];
  const float* y0  = (const float*)d_in[1];
  const float* wl0 = (const float*)d_in[2];
  const float* x1  = (const float*)d_in[3];
  const float* y1  = (const float*)d_in[4];
  const float* wl1 = (const float*)d_in[5];
  const float* x2  = (const float*)d_in[6];
  const float* y2  = (const float*)d_in[7];
  const float* wl2 = (const float*)d_in[8];
  const float* x3  = (const float*)d_in[9];
  const float* y3  = (const float*)d_in[10];
  const float* wl3 = (const float*)d_in[11];
  const float* ws  = (const float*)d_in[12];
  const int* edge_index = (const int*)d_in[13];
  float* out = (float*)d_out;

  __hip_bfloat16* m_i  = (__hip_bfloat16*)d_ws;
  __hip_bfloat16* Tbuf = (__hip_bfloat16*)((char*)d_ws + MI_BYTES);
  __hip_bfloat16* xT   = (__hip_bfloat16*)((char*)d_ws + MI_BYTES + TB_BYTES);
  int* csr_off = (int*)((char*)d_ws + OFF_OFF);
  int* cursor  = (int*)((char*)d_ws + CUR_OFF);
  int* pack    = (int*)((char*)d_ws + PACK_OFF);

  const float* cg_pack;
  if (g_cg_ok) {
    cg_pack = g_cg_dev;
  } else {
    float* cg_ws = (float*)((char*)d_ws + CGP_OFF);
    hipMemcpyAsync(cg_ws, host_pack, sizeof(host_pack), hipMemcpyHostToDevice, stream);
    cg_pack = cg_ws;
  }

  prep_kernel<<<NEDGES + NNODES, 256, 0, stream>>>(y0, y1, y2, y3, x0, x1, x2, x3,
                                                   cg_pack, Tbuf, xT);
  scan_kernel<<<1, 256, 0, stream>>>(edge_index, csr_off, cursor);
  fill_kernel<<<NEDGES / 256, 256, 0, stream>>>(edge_index, cursor, pack);
  tp_node_kernel<<<NNODES, 256, 0, stream>>>(ws, (const unsigned short*)xT,
                                             (const unsigned short*)Tbuf, csr_off, pack, m_i);
  lin_fused_kernel<<<1024, 256, 0, stream>>>((const unsigned short*)m_i,
                                             wl0, wl1, wl2, wl3, out);
}

// Round 6
// 249.109 us; speedup vs baseline: 3.1415x; 1.3266x over previous
//
#include <hip/hip_runtime.h>
#include <hip/hip_bf16.h>
#include <cmath>
#include <cstdint>

#define NNODES 2048
#define NEDGES 8192
#define NCH 64
#define NHID 64
#define NPATH 34
#define NTASK (NPATH * NCH)   // 2176
#define CGTOT 3436
#define MROW 9984
#define TTOT2 888             // per-edge T row, per-path 8-aligned
#define EBLK 8                // edges staged in LDS per chunk

#define MI_BYTES ((size_t)NNODES * MROW * 2)          // 40,894,464
#define TB_BYTES ((size_t)NEDGES * TTOT2 * 2)         // 14,548,992
#define XT_BYTES ((size_t)NNODES * 16 * NCH * 2)      //  4,194,304
#define OFF_OFF  (MI_BYTES + TB_BYTES + XT_BYTES)
#define CUR_OFF  (OFF_OFF + 2052 * 4)
#define PACK_OFF (CUR_OFF + 2048 * 4)
#define ORD_OFF  (PACK_OFF + 8192 * 4)
#define CGP_OFF  (ORD_OFF + 2048 * 4)
#define CGP_FLOATS (TTOT2 * 9)

typedef __attribute__((ext_vector_type(8))) short short8;
typedef __attribute__((ext_vector_type(4))) float floatx4;

// ---------------- path tables (compile-time) ----------------
struct PathTables {
  int l1[NPATH], l2[NPATH], l3[NPATH];
  int cg_off[NPATH], t_off2[NPATH], rank[NPATH];
  int gpaths[2][20], gnp[2], gbase[2], glen[2];
  int cg_total, ttot2, npaths;
};

constexpr PathTables make_tables() {
  PathTables tb{};
  int np = 0;
  for (int a = 0; a < 4; ++a)
    for (int b = 0; b < 4; ++b) {
      int lo = a > b ? a - b : b - a;
      int hi = a + b < 3 ? a + b : 3;
      for (int c = lo; c <= hi; ++c) { tb.l1[np] = a; tb.l2[np] = b; tb.l3[np] = c; ++np; }
    }
  int cg = 0;
  int cnt[4] = {0, 0, 0, 0};
  for (int i = 0; i < np; ++i) {
    tb.cg_off[i] = cg; tb.rank[i] = cnt[tb.l3[i]]++;
    cg += (2 * tb.l1[i] + 1) * (2 * tb.l2[i] + 1) * (2 * tb.l3[i] + 1);
  }
  // group 0: l3 in {0,3}; group 1: l3 in {1,2}; offsets contiguous per group
  int tt2 = 0;
  for (int g = 0; g < 2; ++g) {
    tb.gbase[g] = tt2;
    for (int i = 0; i < np; ++i) {
      int gi = (tb.l3[i] == 0 || tb.l3[i] == 3) ? 0 : 1;
      if (gi != g) continue;
      tb.gpaths[g][tb.gnp[g]++] = i;
      tb.t_off2[i] = tt2;
      int d1 = 2 * tb.l1[i] + 1, d3 = 2 * tb.l3[i] + 1;
      tt2 += ((d1 * d3 + 7) / 8) * 8;
    }
    tb.glen[g] = tt2 - tb.gbase[g];
  }
  tb.cg_total = cg; tb.ttot2 = tt2; tb.npaths = np;
  return tb;
}

constexpr PathTables H_TB = make_tables();
static_assert(H_TB.npaths == NPATH, "npaths");
static_assert(H_TB.cg_total == CGTOT, "cgtot");
static_assert(H_TB.ttot2 == TTOT2, "ttot2");
static_assert(H_TB.gnp[0] == 14 && H_TB.gnp[1] == 20, "gnp");
static_assert(H_TB.gbase[1] == 432 && H_TB.glen[1] == 456, "gsplit");

__constant__ PathTables d_tb = make_tables();

// ---------------- NumPy legacy RandomState(1234) reproduction (host) ----------------
namespace {
struct MT19937 {
  uint32_t mt[624]; int mti; bool has_g; double gval;
  void seed(uint32_t s) {
    for (int i = 0; i < 624; ++i) { mt[i] = s; s = 1812433253u * (s ^ (s >> 30)) + (uint32_t)i + 1u; }
    mti = 624; has_g = false; gval = 0.0;
  }
  uint32_t next() {
    if (mti >= 624) {
      for (int i = 0; i < 624; ++i) {
        uint32_t y = (mt[i] & 0x80000000u) | (mt[(i + 1) % 624] & 0x7fffffffu);
        mt[i] = mt[(i + 397) % 624] ^ (y >> 1) ^ ((y & 1u) ? 0x9908b0dfu : 0u);
      }
      mti = 0;
    }
    uint32_t y = mt[mti++];
    y ^= y >> 11; y ^= (y << 7) & 0x9d2c5680u; y ^= (y << 15) & 0xefc60000u; y ^= y >> 18;
    return y;
  }
  double rdbl() {
    uint32_t a = next() >> 5, b = next() >> 6;
    return ((double)a * 67108864.0 + (double)b) / 9007199254740992.0;
  }
  double gauss() {
    if (has_g) { has_g = false; return gval; }
    double x1, x2, r2;
    do {
      x1 = 2.0 * rdbl() - 1.0;
      x2 = 2.0 * rdbl() - 1.0;
      r2 = x1 * x1 + x2 * x2;
    } while (r2 >= 1.0 || r2 == 0.0);
    double f = std::sqrt(-2.0 * std::log(r2) / r2);
    gval = f * x1; has_g = true;
    return f * x2;
  }
};

float host_pack[CGP_FLOATS];
float* g_cg_dev = nullptr;
bool g_cg_ok = false;

struct CGInit {
  CGInit() {
    static float cg[CGTOT];
    MT19937 g; g.seed(1234u);
    int idx = 0;
    for (int i = 0; i < NPATH; ++i) {
      int d1 = 2 * H_TB.l1[i] + 1, d2 = 2 * H_TB.l2[i] + 1, d3 = 2 * H_TB.l3[i] + 1;
      int sz = d1 * d2 * d3;
      for (int k = 0; k < sz; ++k) cg[idx++] = (float)(g.gauss() * 0.2);
    }
    const int ybase[4] = {0, 1, 4, 9};
    for (int k = 0; k < CGP_FLOATS; ++k) host_pack[k] = 0.f;
    for (int i = 0; i < NPATH; ++i) {
      int d1 = 2 * H_TB.l1[i] + 1, d2 = 2 * H_TB.l2[i] + 1, d3 = 2 * H_TB.l3[i] + 1;
      for (int l = 0; l < d1; ++l)
        for (int n3 = 0; n3 < d3; ++n3) {
          int tt2 = H_TB.t_off2[i] + l * d3 + n3;
          for (int m = 0; m < d2; ++m)
            host_pack[tt2 * 8 + m] = cg[H_TB.cg_off[i] + l * d2 * d3 + m * d3 + n3];
          host_pack[TTOT2 * 8 + tt2] = (float)ybase[H_TB.l2[i]];
        }
    }
    (void)hipHostRegister(host_pack, sizeof(host_pack), hipHostRegisterDefault);
    void* p = nullptr;
    if (hipMalloc(&p, sizeof(host_pack)) == hipSuccess && p) {
      if (hipMemcpy(p, host_pack, sizeof(host_pack), hipMemcpyHostToDevice) == hipSuccess) {
        float back = -1.f;
        if (hipMemcpy(&back, (float*)p + (CGP_FLOATS - 1), sizeof(float),
                      hipMemcpyDeviceToHost) == hipSuccess && back == host_pack[CGP_FLOATS - 1]) {
          g_cg_dev = (float*)p;
          g_cg_ok = true;
        }
      }
    }
  }
} cg_init_instance;
}  // namespace

__device__ __forceinline__ float bf2f(unsigned short u) {
  union { unsigned int i; float f; } v; v.i = ((unsigned int)u) << 16; return v.f;
}
__device__ __forceinline__ unsigned short f2bf(float f) {
  __hip_bfloat16 h = __float2bfloat16(f);
  union { __hip_bfloat16 h; unsigned short u; } v; v.h = h; return v.u;
}

// ---------------- kernel 0: prep — per-edge T (bf16) + per-node xT (bf16) ----------------
__global__ __launch_bounds__(256) void prep_kernel(
    const float* __restrict__ y0, const float* __restrict__ y1,
    const float* __restrict__ y2, const float* __restrict__ y3,
    const float* __restrict__ x0, const float* __restrict__ x1,
    const float* __restrict__ x2, const float* __restrict__ x3,
    const float* __restrict__ cg_pack,
    __hip_bfloat16* __restrict__ Tbuf, __hip_bfloat16* __restrict__ xT)
{
  const int b = blockIdx.x;
  const int t = threadIdx.x;
  if (b < NEDGES) {
    __shared__ float y_s[17];
    const int e = b;
    if (t == 16) y_s[16] = 0.f;
    if (t < 16) {
      float v;
      if (t < 1)      v = y0[e];
      else if (t < 4) v = y1[e * 3 + (t - 1)];
      else if (t < 9) v = y2[e * 5 + (t - 4)];
      else            v = y3[e * 7 + (t - 9)];
      y_s[t] = v;
    }
    __syncthreads();
    const float* __restrict__ metaf = cg_pack + TTOT2 * 8;
    __hip_bfloat16* To = Tbuf + (size_t)e * TTOT2;
    for (int tt2 = t; tt2 < TTOT2; tt2 += 256) {
      const float4 a = *(const float4*)(cg_pack + tt2 * 8);
      const float4 c = *(const float4*)(cg_pack + tt2 * 8 + 4);
      const int yb = (int)metaf[tt2];
      float acc = a.x * y_s[yb]     + a.y * y_s[yb + 1] + a.z * y_s[yb + 2] + a.w * y_s[yb + 3]
                + c.x * y_s[yb + 4] + c.y * y_s[yb + 5] + c.z * y_s[yb + 6] + c.w * y_s[yb + 7];
      To[tt2] = __float2bfloat16(acc);
    }
  } else {
    const int n = b - NEDGES;
    for (int idx = t; idx < 1024; idx += 256) {
      const int j = idx >> 6, c = idx & 63;
      const float* src; int d1, m;
      if (j < 1)      { src = x0; d1 = 1; m = j; }
      else if (j < 4) { src = x1; d1 = 3; m = j - 1; }
      else if (j < 9) { src = x2; d1 = 5; m = j - 4; }
      else            { src = x3; d1 = 7; m = j - 9; }
      const float v = src[((size_t)n * NCH + c) * d1 + m];
      xT[((size_t)n * 16 + j) * NCH + c] = __float2bfloat16(v);
    }
  }
}

// ---------------- kernel 0b/0c: CSR build + degree-descending order ----------------
__global__ __launch_bounds__(256) void scan_kernel(
    const int* __restrict__ edge_index, int* __restrict__ off, int* __restrict__ cursor,
    int* __restrict__ order)
{
  __shared__ int ldeg[NNODES];
  __shared__ int csum[256];
  __shared__ int hist[64];
  const int t = threadIdx.x;
  for (int i = t; i < NNODES; i += 256) ldeg[i] = 0;
  __syncthreads();
  const int* __restrict__ dsts = edge_index + NEDGES;
  for (int e = t; e < NEDGES; e += 256) atomicAdd(&ldeg[dsts[e]], 1);
  __syncthreads();
  int loc[8], s = 0;
  const int base0 = t * 8;
#pragma unroll
  for (int j = 0; j < 8; ++j) { loc[j] = ldeg[base0 + j]; s += loc[j]; }
  csum[t] = s;
  __syncthreads();
  for (int o = 1; o < 256; o <<= 1) {
    int v = (t >= o) ? csum[t - o] : 0;
    __syncthreads();
    csum[t] += v;
    __syncthreads();
  }
  int run = csum[t] - s;
#pragma unroll
  for (int j = 0; j < 8; ++j) { off[base0 + j] = run; cursor[base0 + j] = run; run += loc[j]; }
  if (t == 0) off[NNODES] = NEDGES;
  // degree-descending order (64 buckets)
  if (t < 64) hist[t] = 0;
  __syncthreads();
  for (int i = t; i < NNODES; i += 256) {
    int d = ldeg[i]; d = d > 63 ? 63 : d;
    atomicAdd(&hist[63 - d], 1);
  }
  __syncthreads();
  if (t == 0) { int r2 = 0; for (int b = 0; b < 64; ++b) { int c = hist[b]; hist[b] = r2; r2 += c; } }
  __syncthreads();
  for (int i = t; i < NNODES; i += 256) {
    int d = ldeg[i]; d = d > 63 ? 63 : d;
    int pos = atomicAdd(&hist[63 - d], 1);
    order[pos] = i;
  }
}

__global__ __launch_bounds__(256) void fill_kernel(
    const int* __restrict__ edge_index, int* __restrict__ cursor, int* __restrict__ pack)
{
  const int e = blockIdx.x * 256 + threadIdx.x;
  if (e >= NEDGES) return;
  const int d = edge_index[NEDGES + e];
  const int s = edge_index[e];
  const int pos = atomicAdd(&cursor[d], 1);
  pack[pos] = e | (s << 13);
}

// ---------------- kernel 1: per-node TP, LDS-staged T, (node, pathgroup) blocks ----------------
template <int D1, int D3>
__device__ __forceinline__ void tp_task_run(
    int wcol, int toff_l, int rank, int nb, const int* __restrict__ epk,
    const float (*Ts)[456], const float* __restrict__ ws,
    const unsigned short* __restrict__ xT,
    int n, bool first, __hip_bfloat16* __restrict__ m_out)
{
  constexpr int Kc = (D3 == 1) ? 256 : (D3 == 3) ? 576 : (D3 == 5) ? 704 : 640;
  constexpr int Rc = (D3 == 1) ? 0 : (D3 == 3) ? 256 : (D3 == 5) ? 1984 : 5504;
  constexpr int JB = (D1 == 1) ? 0 : (D1 == 3) ? 1 : (D1 == 5) ? 4 : 9;
  const int c = wcol & 63;

  float acc[D3];
#pragma unroll
  for (int m = 0; m < D3; ++m) acc[m] = 0.f;

  for (int ei = 0; ei < nb; ++ei) {
    const int pk = epk[ei];
    const int e = pk & 8191;
    const int s = pk >> 13;
    const float w = ws[(size_t)e * NTASK + wcol];
    const unsigned short* __restrict__ xr = xT + ((size_t)s * 16 + JB) * NCH + c;
    const float* __restrict__ Tp = &Ts[ei][toff_l];
    float u[D3];
#pragma unroll
    for (int m = 0; m < D3; ++m) u[m] = 0.f;
#pragma unroll
    for (int l = 0; l < D1; ++l) {
      const float xv = bf2f(xr[l * NCH]);
#pragma unroll
      for (int m = 0; m < D3; ++m) u[m] += xv * Tp[l * D3 + m];
    }
#pragma unroll
    for (int m = 0; m < D3; ++m) acc[m] += w * u[m];
  }

  __hip_bfloat16* mo = m_out + (size_t)n * MROW + Rc + rank * NCH + c;
  if (first) {
#pragma unroll
    for (int m = 0; m < D3; ++m) mo[m * Kc] = __float2bfloat16(acc[m]);
  } else {
#pragma unroll
    for (int m = 0; m < D3; ++m)
      mo[m * Kc] = __float2bfloat16(__bfloat162float(mo[m * Kc]) + acc[m]);
  }
}

__global__ __launch_bounds__(256) void tp_node_kernel(
    const float* __restrict__ ws, const unsigned short* __restrict__ xT,
    const unsigned short* __restrict__ Tbuf,
    const int* __restrict__ off, const int* __restrict__ pack,
    const int* __restrict__ order,
    __hip_bfloat16* __restrict__ m_out)
{
  __shared__ float Ts[EBLK][456];   // 14.6 KB
  __shared__ int epk[EBLK];

  const int bid = blockIdx.x;
  const int n = order[bid >> 1];
  const int g = bid & 1;
  const int t = threadIdx.x;
  const int beg = off[n];
  const int cnt = off[n + 1] - beg;
  const int gbase2 = d_tb.gbase[g] >> 1;       // dword offset in Tbuf row
  const int glen2  = d_tb.glen[g] >> 1;
  const int ntask  = d_tb.gnp[g] << 6;

  for (int base = 0; base == 0 || base < cnt; base += EBLK) {
    int nb = cnt - base;
    nb = nb < 0 ? 0 : (nb > EBLK ? EBLK : nb);
    if (t < nb) epk[t] = pack[beg + base + t];
    __syncthreads();
    for (int ei = 0; ei < nb; ++ei) {
      const unsigned int* __restrict__ src =
          (const unsigned int*)Tbuf + (size_t)(epk[ei] & 8191) * (TTOT2 / 2) + gbase2;
      for (int j = t; j < glen2; j += 256) {
        const unsigned int v = src[j];
        float2 f2 = make_float2(bf2f((unsigned short)(v & 0xffffu)),
                                bf2f((unsigned short)(v >> 16)));
        *(float2*)&Ts[ei][2 * j] = f2;
      }
    }
    __syncthreads();

    const bool first = (base == 0);
    for (int k = 0; k * 256 + t < ntask; ++k) {
      const int tl = k * 256 + t;
      const int i = d_tb.gpaths[g][tl >> 6];   // wave-uniform
      const int wcol = (i << 6) | (tl & 63);
      const int toff_l = d_tb.t_off2[i] - d_tb.gbase[g];
      const int rk = d_tb.rank[i];
      const int code = d_tb.l1[i] * 4 + d_tb.l3[i];
      switch (code) {
        case  0: tp_task_run<1,1>(wcol, toff_l, rk, nb, epk, Ts, ws, xT, n, first, m_out); break;
        case  1: tp_task_run<1,3>(wcol, toff_l, rk, nb, epk, Ts, ws, xT, n, first, m_out); break;
        case  2: tp_task_run<1,5>(wcol, toff_l, rk, nb, epk, Ts, ws, xT, n, first, m_out); break;
        case  3: tp_task_run<1,7>(wcol, toff_l, rk, nb, epk, Ts, ws, xT, n, first, m_out); break;
        case  4: tp_task_run<3,1>(wcol, toff_l, rk, nb, epk, Ts, ws, xT, n, first, m_out); break;
        case  5: tp_task_run<3,3>(wcol, toff_l, rk, nb, epk, Ts, ws, xT, n, first, m_out); break;
        case  6: tp_task_run<3,5>(wcol, toff_l, rk, nb, epk, Ts, ws, xT, n, first, m_out); break;
        case  7: tp_task_run<3,7>(wcol, toff_l, rk, nb, epk, Ts, ws, xT, n, first, m_out); break;
        case  8: tp_task_run<5,1>(wcol, toff_l, rk, nb, epk, Ts, ws, xT, n, first, m_out); break;
        case  9: tp_task_run<5,3>(wcol, toff_l, rk, nb, epk, Ts, ws, xT, n, first, m_out); break;
        case 10: tp_task_run<5,5>(wcol, toff_l, rk, nb, epk, Ts, ws, xT, n, first, m_out); break;
        case 11: tp_task_run<5,7>(wcol, toff_l, rk, nb, epk, Ts, ws, xT, n, first, m_out); break;
        case 12: tp_task_run<7,1>(wcol, toff_l, rk, nb, epk, Ts, ws, xT, n, first, m_out); break;
        case 13: tp_task_run<7,3>(wcol, toff_l, rk, nb, epk, Ts, ws, xT, n, first, m_out); break;
        case 14: tp_task_run<7,5>(wcol, toff_l, rk, nb, epk, Ts, ws, xT, n, first, m_out); break;
        default: tp_task_run<7,7>(wcol, toff_l, rk, nb, epk, Ts, ws, xT, n, first, m_out); break;
      }
    }
    __syncthreads();
  }
}

// ---------------- kernel 2: fused per-l3 linear — MFMA bf16 ----------------
// 64-row tiles, 4 waves, each wave: 16 rows × 64 cols via 4 MFMA 16x16x32 n-tiles.
template <int D3, int K, int ROFF>
__device__ __forceinline__ void lin_mfma_body(
    int blk, const unsigned short* __restrict__ mu, const float* __restrict__ wl,
    float* __restrict__ out, unsigned short (*A_s)[72], unsigned short (*W_s)[72])
{
  const int t = threadIdx.x;
  const int wv = t >> 6;
  const int lane = t & 63;
  const int idx16 = lane & 15;
  const int quad = lane >> 4;
  const int r0 = blk * 64;

  floatx4 acc[4] = {{0.f,0.f,0.f,0.f},{0.f,0.f,0.f,0.f},{0.f,0.f,0.f,0.f},{0.f,0.f,0.f,0.f}};

  for (int k0 = 0; k0 < K; k0 += 64) {
    // stage A: 64 rows x 64 k (bf16), 512 x 16B items
    for (int idx = t; idx < 512; idx += 256) {
      const int rr = idx >> 3, ck = (idx & 7) * 8;
      const int r = r0 + rr;
      const int nn = r / D3, mm = r - nn * D3;
      const uint4 v = *(const uint4*)(mu + (size_t)nn * MROW + ROFF + mm * K + k0 + ck);
      *(uint4*)&A_s[rr][ck] = v;
    }
    // stage W transposed: W_s[h][k] bf16; thread = (h, kg of 16 k)
    {
      const int h = t & 63, kg = t >> 6;
      unsigned short tmp[16];
#pragma unroll
      for (int j = 0; j < 16; ++j)
        tmp[j] = f2bf(wl[(size_t)(k0 + kg * 16 + j) * 64 + h]);
      *(uint4*)&W_s[h][kg * 16]     = *(const uint4*)&tmp[0];
      *(uint4*)&W_s[h][kg * 16 + 8] = *(const uint4*)&tmp[8];
    }
    __syncthreads();
#pragma unroll
    for (int ks = 0; ks < 2; ++ks) {
      const int kb = ks * 32 + quad * 8;
      const short8 af = *(const short8*)&A_s[wv * 16 + idx16][kb];
#pragma unroll
      for (int nt = 0; nt < 4; ++nt) {
        const short8 bf = *(const short8*)&W_s[nt * 16 + idx16][kb];
        acc[nt] = __builtin_amdgcn_mfma_f32_16x16x32_bf16(af, bf, acc[nt], 0, 0, 0);
      }
    }
    __syncthreads();
  }

#pragma unroll
  for (int nt = 0; nt < 4; ++nt) {
    const int h = nt * 16 + idx16;
#pragma unroll
    for (int r = 0; r < 4; ++r) {
      const int row = r0 + wv * 16 + quad * 4 + r;
      const int nn = row / D3, mm = row - nn * D3;
      out[((size_t)nn * NHID + h) * D3 + mm] = acc[nt][r];
    }
  }
}

// segments (64-row tiles): l3=0: [0,32) | l3=1: [32,128) | l3=2: [128,288) | l3=3: [288,512)
__global__ __launch_bounds__(256) void lin_fused_kernel(
    const unsigned short* __restrict__ mu,
    const float* __restrict__ wl0, const float* __restrict__ wl1,
    const float* __restrict__ wl2, const float* __restrict__ wl3,
    float* __restrict__ out)
{
  __shared__ unsigned short A_s[64][72];
  __shared__ unsigned short W_s[64][72];
  const int b = blockIdx.x;
  if (b < 32)       lin_mfma_body<1, 256, 0>   (b,       mu, wl0, out,           A_s, W_s);
  else if (b < 128) lin_mfma_body<3, 576, 256> (b - 32,  mu, wl1, out + 131072,  A_s, W_s);
  else if (b < 288) lin_mfma_body<5, 704, 1984>(b - 128, mu, wl2, out + 524288,  A_s, W_s);
  else              lin_mfma_body<7, 640, 5504>(b - 288, mu, wl3, out + 1179648, A_s, W_s);
}

// ---------------- launch ----------------
extern "C" void kernel_launch(void* const* d_in, const int* in_sizes, int n_in,
                              void* d_out, int out_size, void* d_ws, size_t ws_size,
                              hipStream_t stream) {
  const float* x0  = (const float*)d_in[0];
  const float* y0  = (const float*)d_in[1];
  const float* wl0 = (const float*)d_in[2];
  const float* x1  = (const float*)d_in[3];
  const float* y1  = (const float*)d_in[4];
  const float* wl1 = (const float*)d_in[5];
  const float* x2  = (const float*)d_in[6];
  const float* y2  = (const float*)d_in[7];
  const float* wl2 = (const float*)d_in[8];
  const float* x3  = (const float*)d_in[9];
  const float* y3  = (const float*)d_in[10];
  const float* wl3 = (const float*)d_in[11];
  const float* ws  = (const float*)d_in[12];
  const int* edge_index = (const int*)d_in[13];
  float* out = (float*)d_out;

  __hip_bfloat16* m_i  = (__hip_bfloat16*)d_ws;
  __hip_bfloat16* Tbuf = (__hip_bfloat16*)((char*)d_ws + MI_BYTES);
  __hip_bfloat16* xT   = (__hip_bfloat16*)((char*)d_ws + MI_BYTES + TB_BYTES);
  int* csr_off = (int*)((char*)d_ws + OFF_OFF);
  int* cursor  = (int*)((char*)d_ws + CUR_OFF);
  int* pack    = (int*)((char*)d_ws + PACK_OFF);
  int* order   = (int*)((char*)d_ws + ORD_OFF);

  const float* cg_pack;
  if (g_cg_ok) {
    cg_pack = g_cg_dev;
  } else {
    float* cg_ws = (float*)((char*)d_ws + CGP_OFF);
    hipMemcpyAsync(cg_ws, host_pack, sizeof(host_pack), hipMemcpyHostToDevice, stream);
    cg_pack = cg_ws;
  }

  prep_kernel<<<NEDGES + NNODES, 256, 0, stream>>>(y0, y1, y2, y3, x0, x1, x2, x3,
                                                   cg_pack, Tbuf, xT);
  scan_kernel<<<1, 256, 0, stream>>>(edge_index, csr_off, cursor, order);
  fill_kernel<<<NEDGES / 256, 256, 0, stream>>>(edge_index, cursor, pack);
  tp_node_kernel<<<2 * NNODES, 256, 0, stream>>>(ws, (const unsigned short*)xT,
                                                 (const unsigned short*)Tbuf,
                                                 csr_off, pack, order, m_i);
  lin_fused_kernel<<<512, 256, 0, stream>>>((const unsigned short*)m_i,
                                            wl0, wl1, wl2, wl3, out);
}

// Round 7
// 233.471 us; speedup vs baseline: 3.3519x; 1.0670x over previous
//
#include <hip/hip_runtime.h>
#include <hip/hip_bf16.h>
#include <cmath>
#include <cstdint>

#define NNODES 2048
#define NEDGES 8192
#define NCH 64
#define NHID 64
#define NPATH 34
#define NTASK (NPATH * NCH)   // 2176
#define CGTOT 3436
#define MROW 9984
#define TTOT2 888             // CGT2 rows, per-path 8-aligned
#define EBLK 8                // edges per LDS chunk

#define MI_BYTES ((size_t)NNODES * MROW * 2)          // 40,894,464
#define XT_BYTES ((size_t)NNODES * 16 * NCH * 2)      //  4,194,304
#define OFF_OFF  (MI_BYTES)
#define CUR_OFF  (OFF_OFF + 2052 * 4)
#define PACK_OFF (CUR_OFF + 2048 * 4)
#define ORD_OFF  (PACK_OFF + 8192 * 4)
#define XT_OFF   (ORD_OFF + 2048 * 4)
#define CGP_OFF  (XT_OFF + XT_BYTES)
#define CGP_FLOATS (TTOT2 * 9)                        // 888*8 CGT2 + 888 meta

typedef __attribute__((ext_vector_type(8))) short short8;
typedef __attribute__((ext_vector_type(4))) float floatx4;

// ---------------- path tables (compile-time) ----------------
struct PathTables {
  int l1[NPATH], l2[NPATH], l3[NPATH];
  int cg_off[NPATH], t_off2[NPATH], rank[NPATH];
  int gpaths[2][20], gnp[2], gbase[2], glen[2];
  int cg_total, ttot2, npaths;
};

constexpr PathTables make_tables() {
  PathTables tb{};
  int np = 0;
  for (int a = 0; a < 4; ++a)
    for (int b = 0; b < 4; ++b) {
      int lo = a > b ? a - b : b - a;
      int hi = a + b < 3 ? a + b : 3;
      for (int c = lo; c <= hi; ++c) { tb.l1[np] = a; tb.l2[np] = b; tb.l3[np] = c; ++np; }
    }
  int cg = 0;
  int cnt[4] = {0, 0, 0, 0};
  for (int i = 0; i < np; ++i) {
    tb.cg_off[i] = cg; tb.rank[i] = cnt[tb.l3[i]]++;
    cg += (2 * tb.l1[i] + 1) * (2 * tb.l2[i] + 1) * (2 * tb.l3[i] + 1);
  }
  // group 0: l3 in {0,3}; group 1: l3 in {1,2}; offsets contiguous per group
  int tt2 = 0;
  for (int g = 0; g < 2; ++g) {
    tb.gbase[g] = tt2;
    for (int i = 0; i < np; ++i) {
      int gi = (tb.l3[i] == 0 || tb.l3[i] == 3) ? 0 : 1;
      if (gi != g) continue;
      tb.gpaths[g][tb.gnp[g]++] = i;
      tb.t_off2[i] = tt2;
      int d1 = 2 * tb.l1[i] + 1, d3 = 2 * tb.l3[i] + 1;
      tt2 += ((d1 * d3 + 7) / 8) * 8;
    }
    tb.glen[g] = tt2 - tb.gbase[g];
  }
  tb.cg_total = cg; tb.ttot2 = tt2; tb.npaths = np;
  return tb;
}

constexpr PathTables H_TB = make_tables();
static_assert(H_TB.npaths == NPATH, "npaths");
static_assert(H_TB.cg_total == CGTOT, "cgtot");
static_assert(H_TB.ttot2 == TTOT2, "ttot2");
static_assert(H_TB.gnp[0] == 14 && H_TB.gnp[1] == 20, "gnp");
static_assert(H_TB.gbase[1] == 432 && H_TB.glen[1] == 456, "gsplit");

__constant__ PathTables d_tb = make_tables();

// ---------------- NumPy legacy RandomState(1234) reproduction (host) ----------------
namespace {
struct MT19937 {
  uint32_t mt[624]; int mti; bool has_g; double gval;
  void seed(uint32_t s) {
    for (int i = 0; i < 624; ++i) { mt[i] = s; s = 1812433253u * (s ^ (s >> 30)) + (uint32_t)i + 1u; }
    mti = 624; has_g = false; gval = 0.0;
  }
  uint32_t next() {
    if (mti >= 624) {
      for (int i = 0; i < 624; ++i) {
        uint32_t y = (mt[i] & 0x80000000u) | (mt[(i + 1) % 624] & 0x7fffffffu);
        mt[i] = mt[(i + 397) % 624] ^ (y >> 1) ^ ((y & 1u) ? 0x9908b0dfu : 0u);
      }
      mti = 0;
    }
    uint32_t y = mt[mti++];
    y ^= y >> 11; y ^= (y << 7) & 0x9d2c5680u; y ^= (y << 15) & 0xefc60000u; y ^= y >> 18;
    return y;
  }
  double rdbl() {
    uint32_t a = next() >> 5, b = next() >> 6;
    return ((double)a * 67108864.0 + (double)b) / 9007199254740992.0;
  }
  double gauss() {
    if (has_g) { has_g = false; return gval; }
    double x1, x2, r2;
    do {
      x1 = 2.0 * rdbl() - 1.0;
      x2 = 2.0 * rdbl() - 1.0;
      r2 = x1 * x1 + x2 * x2;
    } while (r2 >= 1.0 || r2 == 0.0);
    double f = std::sqrt(-2.0 * std::log(r2) / r2);
    gval = f * x1; has_g = true;
    return f * x2;
  }
};

float host_pack[CGP_FLOATS];
float* g_cg_dev = nullptr;
bool g_cg_ok = false;

struct CGInit {
  CGInit() {
    static float cg[CGTOT];
    MT19937 g; g.seed(1234u);
    int idx = 0;
    for (int i = 0; i < NPATH; ++i) {
      int d1 = 2 * H_TB.l1[i] + 1, d2 = 2 * H_TB.l2[i] + 1, d3 = 2 * H_TB.l3[i] + 1;
      int sz = d1 * d2 * d3;
      for (int k = 0; k < sz; ++k) cg[idx++] = (float)(g.gauss() * 0.2);
    }
    const int ybase[4] = {0, 1, 4, 9};
    for (int k = 0; k < CGP_FLOATS; ++k) host_pack[k] = 0.f;
    for (int i = 0; i < NPATH; ++i) {
      int d1 = 2 * H_TB.l1[i] + 1, d2 = 2 * H_TB.l2[i] + 1, d3 = 2 * H_TB.l3[i] + 1;
      for (int l = 0; l < d1; ++l)
        for (int n3 = 0; n3 < d3; ++n3) {
          int tt2 = H_TB.t_off2[i] + l * d3 + n3;
          for (int m = 0; m < d2; ++m)
            host_pack[tt2 * 8 + m] = cg[H_TB.cg_off[i] + l * d2 * d3 + m * d3 + n3];
          host_pack[TTOT2 * 8 + tt2] = (float)ybase[H_TB.l2[i]];
        }
    }
    (void)hipHostRegister(host_pack, sizeof(host_pack), hipHostRegisterDefault);
    void* p = nullptr;
    if (hipMalloc(&p, sizeof(host_pack)) == hipSuccess && p) {
      if (hipMemcpy(p, host_pack, sizeof(host_pack), hipMemcpyHostToDevice) == hipSuccess) {
        float back = -1.f;
        if (hipMemcpy(&back, (float*)p + (CGP_FLOATS - 1), sizeof(float),
                      hipMemcpyDeviceToHost) == hipSuccess && back == host_pack[CGP_FLOATS - 1]) {
          g_cg_dev = (float*)p;
          g_cg_ok = true;
        }
      }
    }
  }
} cg_init_instance;
}  // namespace

__device__ __forceinline__ float bf2f(unsigned short u) {
  union { unsigned int i; float f; } v; v.i = ((unsigned int)u) << 16; return v.f;
}
__device__ __forceinline__ unsigned short f2bf(float f) {
  __hip_bfloat16 h = __float2bfloat16(f);
  union { __hip_bfloat16 h; unsigned short u; } v; v.h = h; return v.u;
}

// ---------------- kernel A: CSR degrees + prefix + degree-descending order ----------------
__global__ __launch_bounds__(1024) void scan_kernel(
    const int* __restrict__ edge_index, int* __restrict__ off, int* __restrict__ cursor,
    int* __restrict__ order)
{
  __shared__ int ldeg[NNODES];
  __shared__ int csum[1024];
  __shared__ int hist[64];
  const int t = threadIdx.x;
  for (int i = t; i < NNODES; i += 1024) ldeg[i] = 0;
  __syncthreads();
  const int* __restrict__ dsts = edge_index + NEDGES;
  for (int e = t; e < NEDGES; e += 1024) atomicAdd(&ldeg[dsts[e]], 1);
  __syncthreads();
  const int l0 = ldeg[2 * t], l1 = ldeg[2 * t + 1];
  const int s = l0 + l1;
  csum[t] = s;
  __syncthreads();
  for (int o = 1; o < 1024; o <<= 1) {
    int v = (t >= o) ? csum[t - o] : 0;
    __syncthreads();
    csum[t] += v;
    __syncthreads();
  }
  int run = csum[t] - s;
  off[2 * t] = run; cursor[2 * t] = run;
  off[2 * t + 1] = run + l0; cursor[2 * t + 1] = run + l0;
  if (t == 0) off[NNODES] = NEDGES;
  // degree-descending order (64 buckets)
  if (t < 64) hist[t] = 0;
  __syncthreads();
  for (int i = t; i < NNODES; i += 1024) {
    int d = ldeg[i]; d = d > 63 ? 63 : d;
    atomicAdd(&hist[63 - d], 1);
  }
  __syncthreads();
  if (t == 0) { int r2 = 0; for (int b = 0; b < 64; ++b) { int c = hist[b]; hist[b] = r2; r2 += c; } }
  __syncthreads();
  for (int i = t; i < NNODES; i += 1024) {
    int d = ldeg[i]; d = d > 63 ? 63 : d;
    int pos = atomicAdd(&hist[63 - d], 1);
    order[pos] = i;
  }
}

// ---------------- kernel B: CSR fill + xT build ----------------
__global__ __launch_bounds__(256) void fill_xt_kernel(
    const int* __restrict__ edge_index, int* __restrict__ cursor, int* __restrict__ pack,
    const float* __restrict__ x0, const float* __restrict__ x1,
    const float* __restrict__ x2, const float* __restrict__ x3,
    __hip_bfloat16* __restrict__ xT)
{
  const int b = blockIdx.x;
  const int t = threadIdx.x;
  if (b < 32) {
    const int e = b * 256 + t;
    const int d = edge_index[NEDGES + e];
    const int s = edge_index[e];
    const int pos = atomicAdd(&cursor[d], 1);
    pack[pos] = e | (s << 13);
  } else {
    const int n = b - 32;
    for (int idx = t; idx < 1024; idx += 256) {
      const int j = idx >> 6, c = idx & 63;   // j wave-uniform
      const float* src; int d1, m;
      if (j < 1)      { src = x0; d1 = 1; m = j; }
      else if (j < 4) { src = x1; d1 = 3; m = j - 1; }
      else if (j < 9) { src = x2; d1 = 5; m = j - 4; }
      else            { src = x3; d1 = 7; m = j - 9; }
      const float v = src[((size_t)n * NCH + c) * d1 + m];
      xT[((size_t)n * 16 + j) * NCH + c] = __float2bfloat16(v);
    }
  }
}

// ---------------- kernel 1: per-node TP, in-kernel T, LDS-staged ----------------
template <int D1, int D3>
__device__ __forceinline__ void tp_task_run(
    int wcol, int toff_l, int rank, int nb, const int* __restrict__ epk,
    const float (*Ts)[456], const float* __restrict__ ws,
    const unsigned short* __restrict__ xT,
    int n, bool first, __hip_bfloat16* __restrict__ m_out)
{
  constexpr int Kc = (D3 == 1) ? 256 : (D3 == 3) ? 576 : (D3 == 5) ? 704 : 640;
  constexpr int Rc = (D3 == 1) ? 0 : (D3 == 3) ? 256 : (D3 == 5) ? 1984 : 5504;
  constexpr int JB = (D1 == 1) ? 0 : (D1 == 3) ? 1 : (D1 == 5) ? 4 : 9;
  const int c = wcol & 63;

  // prefetch all edge weights (ws is the cold 71 MB stream) — 8 loads in flight
  float wv_[EBLK];
#pragma unroll
  for (int ei = 0; ei < EBLK; ++ei)
    wv_[ei] = (ei < nb) ? ws[(size_t)(epk[ei] & 8191) * NTASK + wcol] : 0.f;

  float acc[D3];
#pragma unroll
  for (int m = 0; m < D3; ++m) acc[m] = 0.f;

  for (int ei = 0; ei < nb; ++ei) {
    const int s = epk[ei] >> 13;
    const unsigned short* __restrict__ xr = xT + ((size_t)s * 16 + JB) * NCH + c;
    const float* __restrict__ Tp = &Ts[ei][toff_l];
    float u[D3];
#pragma unroll
    for (int m = 0; m < D3; ++m) u[m] = 0.f;
#pragma unroll
    for (int l = 0; l < D1; ++l) {
      const float xv = bf2f(xr[l * NCH]);
#pragma unroll
      for (int m = 0; m < D3; ++m) u[m] += xv * Tp[l * D3 + m];
    }
#pragma unroll
    for (int m = 0; m < D3; ++m) acc[m] += wv_[ei] * u[m];
  }

  __hip_bfloat16* mo = m_out + (size_t)n * MROW + Rc + rank * NCH + c;
  if (first) {
#pragma unroll
    for (int m = 0; m < D3; ++m) mo[m * Kc] = __float2bfloat16(acc[m]);
  } else {
#pragma unroll
    for (int m = 0; m < D3; ++m)
      mo[m * Kc] = __float2bfloat16(__bfloat162float(mo[m * Kc]) + acc[m]);
  }
}

__global__ __launch_bounds__(256) void tp_node_kernel(
    const float* __restrict__ y0, const float* __restrict__ y1,
    const float* __restrict__ y2, const float* __restrict__ y3,
    const float* __restrict__ ws, const unsigned short* __restrict__ xT,
    const float* __restrict__ cg_pack,
    const int* __restrict__ off, const int* __restrict__ pack,
    const int* __restrict__ order,
    __hip_bfloat16* __restrict__ m_out)
{
  __shared__ float Ts[EBLK][456];   // 14.6 KB
  __shared__ float y_s[EBLK][18];
  __shared__ int epk[EBLK];

  const int bid = blockIdx.x;
  const int n = order[bid >> 1];
  const int g = bid & 1;
  const int t = threadIdx.x;
  const int beg = off[n];
  const int cnt = off[n + 1] - beg;
  const int gbase = d_tb.gbase[g];
  const int glen  = d_tb.glen[g];
  const int ntask = d_tb.gnp[g] << 6;
  const float* __restrict__ metaf = cg_pack + TTOT2 * 8;

  for (int base = 0; base == 0 || base < cnt; base += EBLK) {
    int nb = cnt - base;
    nb = nb < 0 ? 0 : (nb > EBLK ? EBLK : nb);
    if (t < nb) epk[t] = pack[beg + base + t];
    if (t >= 64 && t < 64 + 2 * EBLK) y_s[(t - 64) >> 1][16 + (t & 1)] = 0.f;
    __syncthreads();
    // stage y for the chunk's edges
    if (t < nb * 16) {
      const int ei = t >> 4, j = t & 15;
      const int e = epk[ei] & 8191;
      float v;
      if (j < 1)      v = y0[e];
      else if (j < 4) v = y1[e * 3 + (j - 1)];
      else if (j < 9) v = y2[e * 5 + (j - 4)];
      else            v = y3[e * 7 + (j - 9)];
      y_s[ei][j] = v;
    }
    __syncthreads();
    // compute T in LDS: Ts[ei][j] = sum_m CGT2[gbase+j][m] * y[ei][yb+m]
    for (int ei = 0; ei < nb; ++ei) {
      for (int j = t; j < glen; j += 256) {
        const int tt2 = gbase + j;
        const float4 a = *(const float4*)(cg_pack + tt2 * 8);
        const float4 c4 = *(const float4*)(cg_pack + tt2 * 8 + 4);
        const int yb = (int)metaf[tt2];
        const float* yy = &y_s[ei][yb];
        Ts[ei][j] = a.x * yy[0] + a.y * yy[1] + a.z * yy[2] + a.w * yy[3]
                  + c4.x * yy[4] + c4.y * yy[5] + c4.z * yy[6] + c4.w * yy[7];
      }
    }
    __syncthreads();

    const bool first = (base == 0);
    for (int k = 0; k * 256 + t < ntask; ++k) {
      const int tl = k * 256 + t;
      const int i = d_tb.gpaths[g][tl >> 6];   // wave-uniform
      const int wcol = (i << 6) | (tl & 63);
      const int toff_l = d_tb.t_off2[i] - gbase;
      const int rk = d_tb.rank[i];
      const int code = d_tb.l1[i] * 4 + d_tb.l3[i];
      switch (code) {
        case  0: tp_task_run<1,1>(wcol, toff_l, rk, nb, epk, Ts, ws, xT, n, first, m_out); break;
        case  1: tp_task_run<1,3>(wcol, toff_l, rk, nb, epk, Ts, ws, xT, n, first, m_out); break;
        case  2: tp_task_run<1,5>(wcol, toff_l, rk, nb, epk, Ts, ws, xT, n, first, m_out); break;
        case  3: tp_task_run<1,7>(wcol, toff_l, rk, nb, epk, Ts, ws, xT, n, first, m_out); break;
        case  4: tp_task_run<3,1>(wcol, toff_l, rk, nb, epk, Ts, ws, xT, n, first, m_out); break;
        case  5: tp_task_run<3,3>(wcol, toff_l, rk, nb, epk, Ts, ws, xT, n, first, m_out); break;
        case  6: tp_task_run<3,5>(wcol, toff_l, rk, nb, epk, Ts, ws, xT, n, first, m_out); break;
        case  7: tp_task_run<3,7>(wcol, toff_l, rk, nb, epk, Ts, ws, xT, n, first, m_out); break;
        case  8: tp_task_run<5,1>(wcol, toff_l, rk, nb, epk, Ts, ws, xT, n, first, m_out); break;
        case  9: tp_task_run<5,3>(wcol, toff_l, rk, nb, epk, Ts, ws, xT, n, first, m_out); break;
        case 10: tp_task_run<5,5>(wcol, toff_l, rk, nb, epk, Ts, ws, xT, n, first, m_out); break;
        case 11: tp_task_run<5,7>(wcol, toff_l, rk, nb, epk, Ts, ws, xT, n, first, m_out); break;
        case 12: tp_task_run<7,1>(wcol, toff_l, rk, nb, epk, Ts, ws, xT, n, first, m_out); break;
        case 13: tp_task_run<7,3>(wcol, toff_l, rk, nb, epk, Ts, ws, xT, n, first, m_out); break;
        case 14: tp_task_run<7,5>(wcol, toff_l, rk, nb, epk, Ts, ws, xT, n, first, m_out); break;
        default: tp_task_run<7,7>(wcol, toff_l, rk, nb, epk, Ts, ws, xT, n, first, m_out); break;
      }
    }
    __syncthreads();
  }
}

// ---------------- kernel 2: fused per-l3 linear — MFMA bf16 ----------------
template <int D3, int K, int ROFF>
__device__ __forceinline__ void lin_mfma_body(
    int blk, const unsigned short* __restrict__ mu, const float* __restrict__ wl,
    float* __restrict__ out, unsigned short (*A_s)[72], unsigned short (*W_s)[72])
{
  const int t = threadIdx.x;
  const int wv = t >> 6;
  const int lane = t & 63;
  const int idx16 = lane & 15;
  const int quad = lane >> 4;
  const int r0 = blk * 64;

  floatx4 acc[4] = {{0.f,0.f,0.f,0.f},{0.f,0.f,0.f,0.f},{0.f,0.f,0.f,0.f},{0.f,0.f,0.f,0.f}};

  for (int k0 = 0; k0 < K; k0 += 64) {
    for (int idx = t; idx < 512; idx += 256) {
      const int rr = idx >> 3, ck = (idx & 7) * 8;
      const int r = r0 + rr;
      const int nn = r / D3, mm = r - nn * D3;
      const uint4 v = *(const uint4*)(mu + (size_t)nn * MROW + ROFF + mm * K + k0 + ck);
      *(uint4*)&A_s[rr][ck] = v;
    }
    {
      const int h = t & 63, kg = t >> 6;
      unsigned short tmp[16];
#pragma unroll
      for (int j = 0; j < 16; ++j)
        tmp[j] = f2bf(wl[(size_t)(k0 + kg * 16 + j) * 64 + h]);
      *(uint4*)&W_s[h][kg * 16]     = *(const uint4*)&tmp[0];
      *(uint4*)&W_s[h][kg * 16 + 8] = *(const uint4*)&tmp[8];
    }
    __syncthreads();
#pragma unroll
    for (int ks = 0; ks < 2; ++ks) {
      const int kb = ks * 32 + quad * 8;
      const short8 af = *(const short8*)&A_s[wv * 16 + idx16][kb];
#pragma unroll
      for (int nt = 0; nt < 4; ++nt) {
        const short8 bf = *(const short8*)&W_s[nt * 16 + idx16][kb];
        acc[nt] = __builtin_amdgcn_mfma_f32_16x16x32_bf16(af, bf, acc[nt], 0, 0, 0);
      }
    }
    __syncthreads();
  }

#pragma unroll
  for (int nt = 0; nt < 4; ++nt) {
    const int h = nt * 16 + idx16;
#pragma unroll
    for (int r = 0; r < 4; ++r) {
      const int row = r0 + wv * 16 + quad * 4 + r;
      const int nn = row / D3, mm = row - nn * D3;
      out[((size_t)nn * NHID + h) * D3 + mm] = acc[nt][r];
    }
  }
}

__global__ __launch_bounds__(256) void lin_fused_kernel(
    const unsigned short* __restrict__ mu,
    const float* __restrict__ wl0, const float* __restrict__ wl1,
    const float* __restrict__ wl2, const float* __restrict__ wl3,
    float* __restrict__ out)
{
  __shared__ unsigned short A_s[64][72];
  __shared__ unsigned short W_s[64][72];
  const int b = blockIdx.x;
  if (b < 32)       lin_mfma_body<1, 256, 0>   (b,       mu, wl0, out,           A_s, W_s);
  else if (b < 128) lin_mfma_body<3, 576, 256> (b - 32,  mu, wl1, out + 131072,  A_s, W_s);
  else if (b < 288) lin_mfma_body<5, 704, 1984>(b - 128, mu, wl2, out + 524288,  A_s, W_s);
  else              lin_mfma_body<7, 640, 5504>(b - 288, mu, wl3, out + 1179648, A_s, W_s);
}

// ---------------- launch ----------------
extern "C" void kernel_launch(void* const* d_in, const int* in_sizes, int n_in,
                              void* d_out, int out_size, void* d_ws, size_t ws_size,
                              hipStream_t stream) {
  const float* x0  = (const float*)d_in[0];
  const float* y0  = (const float*)d_in[1];
  const float* wl0 = (const float*)d_in[2];
  const float* x1  = (const float*)d_in[3];
  const float* y1  = (const float*)d_in[4];
  const float* wl1 = (const float*)d_in[5];
  const float* x2  = (const float*)d_in[6];
  const float* y2  = (const float*)d_in[7];
  const float* wl2 = (const float*)d_in[8];
  const float* x3  = (const float*)d_in[9];
  const float* y3  = (const float*)d_in[10];
  const float* wl3 = (const float*)d_in[11];
  const float* ws  = (const float*)d_in[12];
  const int* edge_index = (const int*)d_in[13];
  float* out = (float*)d_out;

  __hip_bfloat16* m_i = (__hip_bfloat16*)d_ws;
  int* csr_off = (int*)((char*)d_ws + OFF_OFF);
  int* cursor  = (int*)((char*)d_ws + CUR_OFF);
  int* pack    = (int*)((char*)d_ws + PACK_OFF);
  int* order   = (int*)((char*)d_ws + ORD_OFF);
  __hip_bfloat16* xT = (__hip_bfloat16*)((char*)d_ws + XT_OFF);

  const float* cg_pack;
  if (g_cg_ok) {
    cg_pack = g_cg_dev;
  } else {
    float* cg_ws = (float*)((char*)d_ws + CGP_OFF);
    hipMemcpyAsync(cg_ws, host_pack, sizeof(host_pack), hipMemcpyHostToDevice, stream);
    cg_pack = cg_ws;
  }

  scan_kernel<<<1, 1024, 0, stream>>>(edge_index, csr_off, cursor, order);
  fill_xt_kernel<<<32 + NNODES, 256, 0, stream>>>(edge_index, cursor, pack,
                                                  x0, x1, x2, x3, xT);
  tp_node_kernel<<<2 * NNODES, 256, 0, stream>>>(y0, y1, y2, y3, ws,
                                                 (const unsigned short*)xT, cg_pack,
                                                 csr_off, pack, order, m_i);
  lin_fused_kernel<<<512, 256, 0, stream>>>((const unsigned short*)m_i,
                                            wl0, wl1, wl2, wl3, out);
}